// Round 4
// baseline (2026.258 us; speedup 1.0000x reference)
//
#include <hip/hip_runtime.h>
#include <math.h>
#include <stdio.h>

#define BB 4
#define NP 65536

typedef unsigned short u16;
typedef unsigned int u32;

__device__ __forceinline__ float bf2f(u16 u) { return __uint_as_float((u32)u << 16); }
__device__ __forceinline__ u16 f2bf(float f) {
  u32 u = __float_as_uint(f);
  u = (u + 0x7FFFu + ((u >> 16) & 1u)) >> 16;
  return (u16)u;
}
__device__ __forceinline__ float gelu_f(float x) {
  return 0.5f * x * (1.f + erff(x * 0.70710678118654752f));
}

// ---------------- transpose (B,N,C)->(B,C,N) + sigma1 fold (xb1=xi*sig bf16) + SCA mean partials
__global__ __launch_bounds__(256) void k_trans_stats(const float* __restrict__ x,
                                                     float* __restrict__ xi,
                                                     u16* __restrict__ xb1,
                                                     float* __restrict__ meanraw) {
  __shared__ float tile[64 * 65];
  __shared__ float s1a[64], s2a[64], sig[64], cm[64];
  int b = blockIdx.y;
  long n0 = (long)blockIdx.x * 64;
  int t = threadIdx.x;
  for (int i = t; i < 4096; i += 256) {
    int nl = i >> 6, c = i & 63;
    tile[nl * 65 + c] = x[((long)b * NP + n0 + nl) * 64 + c];
  }
  if (t < 64) { s1a[t] = 0.f; s2a[t] = 0.f; cm[t] = 0.f; }
  __syncthreads();
  {
    int nl = t & 63, part = t >> 6;
    float p1 = 0.f, p2 = 0.f;
    for (int cc = 0; cc < 16; cc++) {
      float v = tile[nl * 65 + part * 16 + cc];
      p1 += v; p2 += v * v;
    }
    atomicAdd(&s1a[nl], p1); atomicAdd(&s2a[nl], p2);
  }
  __syncthreads();
  if (t < 64) {
    float m = s1a[t] * (1.f / 64.f);
    float var = s2a[t] * (1.f / 64.f) - m * m;
    sig[t] = rsqrtf(var + 1e-5f);
  }
  __syncthreads();
  int nl = t & 63;
  float sgv = sig[nl];
  for (int j = 0; j < 16; j++) {
    int i = t + 256 * j;
    int c = i >> 6;
    float v = tile[nl * 65 + c];
    xi[((long)b * 64 + c) * NP + n0 + nl] = v;
    float xbv = v * sgv;
    xb1[((long)b * 64 + c) * NP + n0 + nl] = f2bf(xbv);
    float a = xbv;
    for (int off = 32; off; off >>= 1) a += __shfl_down(a, off);
    if ((t & 63) == 0) atomicAdd(&cm[c], a);
  }
  __syncthreads();
  if (t < 64) atomicAdd(&meanraw[b * 64 + t], cm[t]);
}

// ---------------- xsca
__global__ void k_xsca(const float* __restrict__ meanraw, const float* __restrict__ lnw,
                       const float* __restrict__ sca_w, const float* __restrict__ sca_b,
                       float* __restrict__ xsca) {
  int t = threadIdx.x;
  int b = t >> 6, co = t & 63;
  float a = sca_b[co];
  for (int ci = 0; ci < 64; ci++)
    a += sca_w[co * 64 + ci] * meanraw[b * 64 + ci] * lnw[ci] * (1.f / 65536.f);
  xsca[t] = a;
}

// ---------------- weight prep
__global__ void k_foldW1(const float* __restrict__ qkv_w, const float* __restrict__ dw1_w,
                         const float* __restrict__ lnw, float* __restrict__ W1T) {
  int i = blockIdx.x * 256 + threadIdx.x;
  if (i < 64 * 320) {
    int ci = i / 320, co = i - ci * 320;
    float w = (co < 192) ? qkv_w[co * 64 + ci] : dw1_w[(co - 192) * 64 + ci];
    W1T[i] = w * lnw[ci];
  }
}
// pin weights pair-interleaved: col 2c -> pin ch c, col 2c+1 -> pin ch c+170; pad to 384
__global__ void k_foldW2(const float* __restrict__ pin_w, const float* __restrict__ lnw,
                         float* __restrict__ W2T) {
  int i = blockIdx.x * 256 + threadIdx.x;
  if (i < 64 * 384) {
    int ci = i / 384, co = i - ci * 384;
    float v = 0.f;
    if (co < 340) {
      int pair = co >> 1, which = co & 1;
      v = pin_w[(pair + which * 170) * 64 + ci] * lnw[ci];
    }
    W2T[i] = v;
  }
}
__global__ void k_tproj(const float* __restrict__ w, float* __restrict__ WpT) {
  int i = blockIdx.x * 256 + threadIdx.x;
  if (i < 4096) { int ci = i >> 6, co = i & 63; WpT[ci * 64 + co] = w[co * 64 + ci]; }
}
__global__ void k_tpout(const float* __restrict__ w, float* __restrict__ WoT) {
  int i = blockIdx.x * 256 + threadIdx.x;
  if (i < 170 * 64) { int ci = i >> 6, co = i & 63; WoT[ci * 64 + co] = w[co * 170 + ci]; }
}

// ---------------- 1x1 GEMM 64->64co chunk, bf16 in/out, s_load weights, all batches
__global__ __launch_bounds__(256) void k_gemm64(const u16* __restrict__ xb,
                                                const float* __restrict__ wT, int Wstride,
                                                u16* __restrict__ P, long P_bs) {
  int n = blockIdx.x * 256 + threadIdx.x;
  int co0 = blockIdx.y * 64;
  int b = blockIdx.z;
  float acc[64];
#pragma unroll
  for (int j = 0; j < 64; j++) acc[j] = 0.f;
  const u16* ip = xb + (long)b * 64 * NP + n;
  const float* wp = wT + co0;
#pragma unroll 2
  for (int ci = 0; ci < 64; ci++) {
    float xv = bf2f(ip[(long)ci * NP]);
    const float* wr = wp + (long)ci * Wstride;
#pragma unroll
    for (int j = 0; j < 64; j++) acc[j] += wr[j] * xv;
  }
  u16* op = P + (long)b * P_bs + (long)co0 * NP + n;
#pragma unroll
  for (int j = 0; j < 64; j++) op[(long)j * NP] = f2bf(acc[j]);
}

// ---------------- depthwise 3x3 helper (bf16 global in, bounds-checked)
__device__ __forceinline__ float dwc3(const u16* __restrict__ p, int y, int x,
                                      const float* __restrict__ w9) {
  float a = 0.f;
#pragma unroll
  for (int dy = -1; dy <= 1; dy++) {
    int yy = y + dy; if ((unsigned)yy >= 256u) continue;
#pragma unroll
    for (int dx = -1; dx <= 1; dx++) {
      int xx = x + dx; if ((unsigned)xx >= 256u) continue;
      a += w9[(dy + 1) * 3 + dx + 1] * bf2f(p[yy * 256 + xx]);
    }
  }
  return a;
}

// ---------------- fused q/k/v depthwise + norm + stats (one head per blockIdx.y)
__global__ __launch_bounds__(256) void k_dwqkv(const u16* __restrict__ P,
                                               const float* __restrict__ dww,
                                               u16* __restrict__ Qn, u16* __restrict__ Kn,
                                               float* __restrict__ stats) {
  int n = blockIdx.x * 256 + threadIdx.x;
  int h = blockIdx.y, b = blockIdx.z;
  int y = n >> 8, x = n & 255;
  int t = threadIdx.x;
  const u16* Pb = P + (long)b * 192 * NP;
  float q[8], k[8], v[8];
  float qs = 0.f, ks2 = 0.f;
#pragma unroll
  for (int c = 0; c < 8; c++) {
    q[c] = dwc3(Pb + (long)(h * 8 + c) * NP, y, x, dww + (h * 8 + c) * 9);
    qs += q[c] * q[c];
  }
#pragma unroll
  for (int c = 0; c < 8; c++) {
    k[c] = dwc3(Pb + (long)(64 + h * 8 + c) * NP, y, x, dww + (64 + h * 8 + c) * 9);
    ks2 += k[c] * k[c];
  }
#pragma unroll
  for (int c = 0; c < 8; c++)
    v[c] = dwc3(Pb + (long)(128 + h * 8 + c) * NP, y, x, dww + (128 + h * 8 + c) * 9);
  float qsc = 1.f / (sqrtf(qs) + 1e-6f);
  float ksc = 1.f / (sqrtf(ks2) + 1e-6f);
#pragma unroll
  for (int c = 0; c < 8; c++) {
    q[c] *= qsc; k[c] *= ksc;
    Qn[((long)b * 64 + h * 8 + c) * NP + n] = f2bf(q[c]);
    Kn[((long)b * 64 + h * 8 + c) * NP + n] = f2bf(k[c]);
  }
  __shared__ float sred[80];
  if (t < 80) sred[t] = 0.f;
  __syncthreads();
#pragma unroll
  for (int i = 0; i < 8; i++)
#pragma unroll
    for (int j = 0; j < 8; j++) {
      float a = k[i] * v[j];
      for (int off = 32; off; off >>= 1) a += __shfl_down(a, off);
      if ((t & 63) == 0) atomicAdd(&sred[i * 8 + j], a);
    }
#pragma unroll
  for (int i = 0; i < 8; i++) {
    float a = k[i];
    for (int off = 32; off; off >>= 1) a += __shfl_down(a, off);
    if ((t & 63) == 0) atomicAdd(&sred[64 + i], a);
    float c2 = v[i];
    for (int off = 32; off; off >>= 1) c2 += __shfl_down(c2, off);
    if ((t & 63) == 0) atomicAdd(&sred[72 + i], c2);
  }
  __syncthreads();
  if (t < 80) atomicAdd(&stats[((long)b * 8 + h) * 80 + t], sred[t]);
}

// ---------------- dw1-pairs -> grouped dw2 3x3 -> gelu
__global__ __launch_bounds__(256) void k_dwg(const u16* __restrict__ P,
                                             const float* __restrict__ dw2_w,
                                             u16* __restrict__ G) {
  int n = blockIdx.x * 256 + threadIdx.x;
  int c = blockIdx.y, b = blockIdx.z;
  int y = n >> 8, x = n & 255;
  const u16* Pb = P + (long)b * 128 * NP;
  float d1 = dwc3(Pb + (long)(2 * c) * NP, y, x, dw2_w + c * 18);
  float d2 = dwc3(Pb + (long)(2 * c + 1) * NP, y, x, dw2_w + c * 18 + 9);
  G[((long)b * 64 + c) * NP + n] = f2bf(gelu_f(d1 + d2));
}

// ---------------- FFN dw pair + gelu gate (pair-interleaved P)
__global__ __launch_bounds__(256) void k_dwgate(const u16* __restrict__ P,
                                                const float* __restrict__ dww,
                                                u16* __restrict__ Hb) {
  int n = blockIdx.x * 256 + threadIdx.x;
  int c = blockIdx.y, b = blockIdx.z;
  int y = n >> 8, x = n & 255;
  const u16* Pb = P + (long)b * 384 * NP;
  float d1 = dwc3(Pb + (long)(2 * c) * NP, y, x, dww + c * 9);
  float d2 = dwc3(Pb + (long)(2 * c + 1) * NP, y, x, dww + (170 + c) * 9);
  Hb[((long)b * 170 + c) * NP + n] = f2bf(gelu_f(d1) * d2);
}

// ---------------- refine conv (3/5/7) + sigmoid: f32 LDS tile, 2 phases of 8 ch
template <int WIN>
__device__ void refine_body(float* tile, const u16* __restrict__ Qh, const u16* __restrict__ Kh,
                            const float* __restrict__ wp, float bias,
                            float* __restrict__ ro, int x0, int y0) {
  const int R = WIN / 2, T = 32 + 2 * R;
  const int PP = (WIN == 7) ? 40 : 36;
  int t = threadIdx.x;
  int oy = t >> 3, ox0 = (t & 7) * 4;
  float a0 = bias, a1 = bias, a2 = bias, a3 = bias;
#pragma unroll
  for (int ph = 0; ph < 2; ph++) {
    const u16* src = ph ? Kh : Qh;
    __syncthreads();
    for (int e = t; e < 8 * T * T; e += 256) {
      int ch = e / (T * T); int r = e - ch * (T * T);
      int yy = r / T, xx = r - yy * T;
      int gy = y0 - R + yy, gx = x0 - R + xx;
      float v = 0.f;
      if ((unsigned)gy < 256u && (unsigned)gx < 256u)
        v = bf2f(src[(long)ch * NP + gy * 256 + gx]);
      tile[ch * T * PP + yy * PP + xx] = v;
    }
    __syncthreads();
    for (int ch = 0; ch < 8; ch++) {
      const float* wc = wp + (ph * 8 + ch) * WIN * WIN;
      const float* tb = tile + ch * T * PP;
#pragma unroll
      for (int dy = 0; dy < WIN; dy++) {
        const float* row = tb + (oy + dy) * PP + ox0;
        float f[12];
        *(float4*)(f) = *(const float4*)(row);
        *(float4*)(f + 4) = *(const float4*)(row + 4);
        if (WIN == 7) *(float4*)(f + 8) = *(const float4*)(row + 8);
#pragma unroll
        for (int dx = 0; dx < WIN; dx++) {
          float w = wc[dy * WIN + dx];
          a0 += w * f[dx]; a1 += w * f[dx + 1]; a2 += w * f[dx + 2]; a3 += w * f[dx + 3];
        }
      }
    }
  }
  float4 o;
  o.x = 1.f / (1.f + expf(-a0)); o.y = 1.f / (1.f + expf(-a1));
  o.z = 1.f / (1.f + expf(-a2)); o.w = 1.f / (1.f + expf(-a3));
  *(float4*)(ro + (long)(y0 + oy) * 256 + x0 + ox0) = o;
}

__global__ __launch_bounds__(256) void k_refine(
    const u16* __restrict__ Qn, const u16* __restrict__ Kn,
    const float* __restrict__ r3w, const float* __restrict__ r3b,
    const float* __restrict__ r5w, const float* __restrict__ r5b,
    const float* __restrict__ r7w, const float* __restrict__ r7b,
    float* __restrict__ refW) {
  __shared__ float tile[12160];   // 8ch * 38 * 40 f32 = 47.5 KB
  int bh = blockIdx.z, b = bh >> 3, h = bh & 7;
  const u16* Qh = Qn + ((long)b * 64 + h * 8) * NP;
  const u16* Kh = Kn + ((long)b * 64 + h * 8) * NP;
  float* ro = refW + (long)bh * NP;
  int x0 = blockIdx.x * 32, y0 = blockIdx.y * 32;
  if (h < 2)      refine_body<3>(tile, Qh, Kh, r3w + h * 16 * 9, r3b[h], ro, x0, y0);
  else if (h < 5) refine_body<5>(tile, Qh, Kh, r5w + (h - 2) * 16 * 25, r5b[h - 2], ro, x0, y0);
  else            refine_body<7>(tile, Qh, Kh, r7w + (h - 5) * 16 * 49, r7b[h - 5], ro, x0, y0);
}

// ---------------- fused attn epilogue + proj GEMM + residual + LN2 + xb2
__global__ __launch_bounds__(256) void k_attnproj(
    const u16* __restrict__ Qn, const float* __restrict__ stats,
    const float* __restrict__ refw, const float* __restrict__ temp,
    const float* __restrict__ xsca, const u16* __restrict__ G,
    const float* __restrict__ WpT, float* __restrict__ xo, u16* __restrict__ xb2) {
  int b = blockIdx.y;
  int t = threadIdx.x;
  __shared__ float s[640];
  __shared__ float sx[64];
  for (int i = t; i < 640; i += 256) s[i] = stats[(long)b * 640 + i];
  if (t < 64) sx[t] = xsca[b * 64 + t];
  __syncthreads();
  long n = (long)blockIdx.x * 256 + t;
  float acc[64];
#pragma unroll
  for (int j = 0; j < 64; j++) acc[j] = 0.f;
#pragma unroll
  for (int h = 0; h < 8; h++) {
    const float* sh = s + h * 80;
    float q[8];
#pragma unroll
    for (int i = 0; i < 8; i++) q[i] = bf2f(Qn[((long)b * 64 + h * 8 + i) * NP + n]);
    float den = 65536.f + 1e-6f;
#pragma unroll
    for (int i = 0; i < 8; i++) den += q[i] * sh[64 + i];
    float tr = temp[h] * refw[((long)b * 8 + h) * NP + n] / den;
#pragma unroll
    for (int j = 0; j < 8; j++) {
      float num = sh[72 + j];
#pragma unroll
      for (int i = 0; i < 8; i++) num += q[i] * sh[i * 8 + j];
      int ci = h * 8 + j;
      float o = num * tr * sx[ci] * bf2f(G[((long)b * 64 + ci) * NP + n]);
      const float* wr = WpT + ci * 64;
#pragma unroll
      for (int co = 0; co < 64; co++) acc[co] += wr[co] * o;
    }
  }
  float* xp = xo + (long)b * 64 * NP + n;
  float s1 = 0.f, s2 = 0.f;
#pragma unroll
  for (int c = 0; c < 64; c++) {
    float v = xp[(long)c * NP] + acc[c];
    acc[c] = v;
    s1 += v; s2 += v * v;
  }
#pragma unroll
  for (int c = 0; c < 64; c++) xp[(long)c * NP] = acc[c];
  float m = s1 * (1.f / 64.f);
  float var = s2 * (1.f / 64.f) - m * m;
  float sg = rsqrtf(var + 1e-5f);
  u16* bp = xb2 + (long)b * 64 * NP + n;
#pragma unroll
  for (int c = 0; c < 64; c++) bp[(long)c * NP] = f2bf(acc[c] * sg);
}

// ---------------- pout GEMM (170->64) + residual
__global__ __launch_bounds__(256) void k_pout(const u16* __restrict__ Hb,
                                              const float* __restrict__ WoT,
                                              float* __restrict__ xo) {
  int n = blockIdx.x * 256 + threadIdx.x;
  int b = blockIdx.z;
  const u16* ip = Hb + (long)b * 170 * NP + n;
  float acc[64];
#pragma unroll
  for (int j = 0; j < 64; j++) acc[j] = 0.f;
#pragma unroll 2
  for (int ci = 0; ci < 170; ci++) {
    float xv = bf2f(ip[(long)ci * NP]);
    const float* wr = WoT + ci * 64;
#pragma unroll
    for (int j = 0; j < 64; j++) acc[j] += wr[j] * xv;
  }
  float* xp = xo + (long)b * 64 * NP + n;
#pragma unroll
  for (int c = 0; c < 64; c++) xp[(long)c * NP] += acc[c];
}

// ================================================================ launcher
extern "C" void kernel_launch(void* const* d_in, const int* in_sizes, int n_in,
                              void* d_out, int out_size, void* d_ws, size_t ws_size,
                              hipStream_t stream) {
  const float* x        = (const float*)d_in[0];
  const float* ln1_w    = (const float*)d_in[1];
  const float* sca_w    = (const float*)d_in[2];
  const float* sca_b    = (const float*)d_in[3];
  const float* dw1_w    = (const float*)d_in[4];
  const float* dw2_w    = (const float*)d_in[5];
  const float* qkv_w    = (const float*)d_in[6];
  const float* qkv_dw_w = (const float*)d_in[7];
  const float* temp     = (const float*)d_in[8];
  const float* r3w = (const float*)d_in[9],  *r3b = (const float*)d_in[10];
  const float* r5w = (const float*)d_in[11], *r5b = (const float*)d_in[12];
  const float* r7w = (const float*)d_in[13], *r7b = (const float*)d_in[14];
  const float* proj_w   = (const float*)d_in[15];
  const float* ln2_w    = (const float*)d_in[16];
  const float* pin_w    = (const float*)d_in[17];
  const float* ffn_dw_w = (const float*)d_in[18];
  const float* pout_w   = (const float*)d_in[19];
  float* out = (float*)d_out;
  char* wsb = (char*)d_ws;

  const size_t Mi = 1048576;
  u16* xb1   = (u16*)(wsb);                 // 32 MiB   (later xb2)
  u16* Qn    = (u16*)(wsb + 32 * Mi);       // 32 MiB   (later Hb start)
  u16* Kn    = (u16*)(wsb + 64 * Mi);
  u16* G     = (u16*)(wsb + 96 * Mi);
  u16* Preg  = (u16*)(wsb + 128 * Mi);      // 96 MiB
  float* refW    = (float*)(wsb + 224 * Mi);// 8 MiB
  float* stats   = (float*)(wsb + 232 * Mi);// 2560
  float* meanraw = stats + 2560;            // 256
  float* xscab   = meanraw + 256;           // 256
  float* W1T     = xscab + 256;             // 64*320
  float* W2T     = W1T + 20480;             // 64*384
  float* WpT     = W2T + 24576;             // 64*64
  float* WoT     = WpT + 4096;              // 170*64
  u16* xb2 = xb1;
  u16* Hb  = Qn;                            // 85 MiB, aliases Qn/Kn/G (dead)

  const size_t needed = 232 * Mi + (size_t)(2560 + 256 + 256 + 20480 + 24576 + 4096 + 10880) * 4;
  if (ws_size < needed) {
    fprintf(stderr, "kernel_launch: ws_size %zu < needed %zu\n", ws_size, needed);
    return;
  }

  hipMemsetAsync(stats, 0, (2560 + 256) * 4, stream);
  k_foldW1<<<80, 256, 0, stream>>>(qkv_w, dw1_w, ln1_w, W1T);
  k_foldW2<<<96, 256, 0, stream>>>(pin_w, ln2_w, W2T);
  k_tproj<<<16, 256, 0, stream>>>(proj_w, WpT);
  k_tpout<<<43, 256, 0, stream>>>(pout_w, WoT);

  k_trans_stats<<<dim3(1024, BB), 256, 0, stream>>>(x, out, xb1, meanraw);
  k_xsca<<<1, 256, 0, stream>>>(meanraw, ln1_w, sca_w, sca_b, xscab);

  // qkv 1x1 (192 co, all batches) -> fused dw+norm+stats
  k_gemm64<<<dim3(256, 3, BB), 256, 0, stream>>>(xb1, W1T, 320, Preg, 192L * NP);
  k_dwqkv<<<dim3(256, 8, BB), 256, 0, stream>>>(Preg, qkv_dw_w, Qn, Kn, stats);

  // dw1 1x1 (128 co) -> grouped dw2 + gelu
  k_gemm64<<<dim3(256, 2, BB), 256, 0, stream>>>(xb1, W1T + 192, 320, Preg, 128L * NP);
  k_dwg<<<dim3(256, 64, BB), 256, 0, stream>>>(Preg, dw2_w, G);

  k_refine<<<dim3(8, 8, 32), 256, 0, stream>>>(Qn, Kn, r3w, r3b, r5w, r5b, r7w, r7b, refW);
  k_attnproj<<<dim3(256, BB), 256, 0, stream>>>(Qn, stats, refW, temp, xscab, G, WpT, out, xb2);

  // FFN: 2 batches per pass (P region holds 384ch x 2 batches)
  for (int b2 = 0; b2 < 2; b2++) {
    k_gemm64<<<dim3(256, 6, 2), 256, 0, stream>>>(xb2 + (long)b2 * 2 * 64 * NP, W2T, 384,
                                                  Preg, 384L * NP);
    k_dwgate<<<dim3(256, 170, 2), 256, 0, stream>>>(Preg, ffn_dw_w,
                                                    Hb + (long)b2 * 2 * 170 * NP);
  }
  k_pout<<<dim3(256, 1, BB), 256, 0, stream>>>(Hb, WoT, out);
}

// Round 5
// 1408.189 us; speedup vs baseline: 1.4389x; 1.4389x over previous
//
#include <hip/hip_runtime.h>
#include <math.h>
#include <stdio.h>

#define BB 4
#define NP 65536

typedef unsigned short u16;
typedef unsigned int u32;

__device__ __forceinline__ float bf2f(u16 u) { return __uint_as_float((u32)u << 16); }
__device__ __forceinline__ u16 f2bf(float f) {
  u32 u = __float_as_uint(f);
  u = (u + 0x7FFFu + ((u >> 16) & 1u)) >> 16;
  return (u16)u;
}
__device__ __forceinline__ float gelu_f(float x) {
  return 0.5f * x * (1.f + erff(x * 0.70710678118654752f));
}

// ---------------- transpose (B,N,C)->(B,C,N) + sigma1 fold + SCA mean partials
__global__ __launch_bounds__(256) void k_trans_stats(const float* __restrict__ x,
                                                     float* __restrict__ xi,
                                                     u16* __restrict__ xb1,
                                                     float* __restrict__ meanraw) {
  __shared__ float tile[64 * 65];
  __shared__ float s1a[64], s2a[64], sig[64], cm[64];
  int b = blockIdx.y;
  long n0 = (long)blockIdx.x * 64;
  int t = threadIdx.x;
  for (int i = t; i < 4096; i += 256) {
    int nl = i >> 6, c = i & 63;
    tile[nl * 65 + c] = x[((long)b * NP + n0 + nl) * 64 + c];
  }
  if (t < 64) { s1a[t] = 0.f; s2a[t] = 0.f; cm[t] = 0.f; }
  __syncthreads();
  {
    int nl = t & 63, part = t >> 6;
    float p1 = 0.f, p2 = 0.f;
    for (int cc = 0; cc < 16; cc++) {
      float v = tile[nl * 65 + part * 16 + cc];
      p1 += v; p2 += v * v;
    }
    atomicAdd(&s1a[nl], p1); atomicAdd(&s2a[nl], p2);
  }
  __syncthreads();
  if (t < 64) {
    float m = s1a[t] * (1.f / 64.f);
    float var = s2a[t] * (1.f / 64.f) - m * m;
    sig[t] = rsqrtf(var + 1e-5f);
  }
  __syncthreads();
  int nl = t & 63;
  float sgv = sig[nl];
  for (int j = 0; j < 16; j++) {
    int i = t + 256 * j;
    int c = i >> 6;
    float v = tile[nl * 65 + c];
    xi[((long)b * 64 + c) * NP + n0 + nl] = v;
    float xbv = v * sgv;
    xb1[((long)b * 64 + c) * NP + n0 + nl] = f2bf(xbv);
    float a = xbv;
    for (int off = 32; off; off >>= 1) a += __shfl_down(a, off);
    if ((t & 63) == 0) atomicAdd(&cm[c], a);
  }
  __syncthreads();
  if (t < 64) atomicAdd(&meanraw[b * 64 + t], cm[t]);
}

// ---------------- xsca
__global__ void k_xsca(const float* __restrict__ meanraw, const float* __restrict__ lnw,
                       const float* __restrict__ sca_w, const float* __restrict__ sca_b,
                       float* __restrict__ xsca) {
  int t = threadIdx.x;
  int b = t >> 6, co = t & 63;
  float a = sca_b[co];
  for (int ci = 0; ci < 64; ci++)
    a += sca_w[co * 64 + ci] * meanraw[b * 64 + ci] * lnw[ci] * (1.f / 65536.f);
  xsca[t] = a;
}

// ---------------- weight prep
__global__ void k_foldW1(const float* __restrict__ qkv_w, const float* __restrict__ dw1_w,
                         const float* __restrict__ lnw, float* __restrict__ W1T) {
  int i = blockIdx.x * 256 + threadIdx.x;
  if (i < 64 * 320) {
    int ci = i / 320, co = i - ci * 320;
    float w = (co < 192) ? qkv_w[co * 64 + ci] : dw1_w[(co - 192) * 64 + ci];
    W1T[i] = w * lnw[ci];
  }
}
__global__ void k_foldW2(const float* __restrict__ pin_w, const float* __restrict__ lnw,
                         float* __restrict__ W2T) {
  int i = blockIdx.x * 256 + threadIdx.x;
  if (i < 64 * 384) {
    int ci = i / 384, co = i - ci * 384;
    float v = 0.f;
    if (co < 340) {
      int pair = co >> 1, which = co & 1;
      v = pin_w[(pair + which * 170) * 64 + ci] * lnw[ci];
    }
    W2T[i] = v;
  }
}
__global__ void k_tproj(const float* __restrict__ w, float* __restrict__ WpT) {
  int i = blockIdx.x * 256 + threadIdx.x;
  if (i < 4096) { int ci = i >> 6, co = i & 63; WpT[ci * 64 + co] = w[co * 64 + ci]; }
}
__global__ void k_tpout(const float* __restrict__ w, float* __restrict__ WoT) {
  int i = blockIdx.x * 256 + threadIdx.x;
  if (i < 170 * 64) { int ci = i >> 6, co = i & 63; WoT[ci * 64 + co] = w[co * 170 + ci]; }
}

// ---------------- 1x1 GEMM 64->64co chunk, bf16 in/out, s_load weights
__global__ __launch_bounds__(256) void k_gemm64(const u16* __restrict__ xb,
                                                const float* __restrict__ wT, int Wstride,
                                                u16* __restrict__ P, long P_bs) {
  int n = blockIdx.x * 256 + threadIdx.x;
  int co0 = blockIdx.y * 64;
  int b = blockIdx.z;
  float acc[64];
#pragma unroll
  for (int j = 0; j < 64; j++) acc[j] = 0.f;
  const u16* ip = xb + (long)b * 64 * NP + n;
  const float* wp = wT + co0;
#pragma unroll 2
  for (int ci = 0; ci < 64; ci++) {
    float xv = bf2f(ip[(long)ci * NP]);
    const float* wr = wp + (long)ci * Wstride;
#pragma unroll
    for (int j = 0; j < 64; j++) acc[j] += wr[j] * xv;
  }
  u16* op = P + (long)b * P_bs + (long)co0 * NP + n;
#pragma unroll
  for (int j = 0; j < 64; j++) op[(long)j * NP] = f2bf(acc[j]);
}

// ---------------- vectorized dw3x3: 4 px/thread, ushort4 loads, shfl halo
// wave (64 lanes) covers one full 256-px row; lane l -> x0 = 4l
__device__ __forceinline__ void dw4(const u16* __restrict__ img, int y, int x0, int lane,
                                    const float* __restrict__ w9, float d[4]) {
  d[0] = 0.f; d[1] = 0.f; d[2] = 0.f; d[3] = 0.f;
#pragma unroll
  for (int dy = -1; dy <= 1; dy++) {
    int r = y + dy;                      // wave-uniform
    float v1, v2, v3, v4;
    if ((unsigned)r < 256u) {
      ushort4 u = *(const ushort4*)(img + r * 256 + x0);
      v1 = bf2f(u.x); v2 = bf2f(u.y); v3 = bf2f(u.z); v4 = bf2f(u.w);
    } else { v1 = 0.f; v2 = 0.f; v3 = 0.f; v4 = 0.f; }
    float v0 = __shfl_up(v4, 1);  if (lane == 0)  v0 = 0.f;
    float v5 = __shfl_down(v1, 1); if (lane == 63) v5 = 0.f;
    float w0 = w9[(dy + 1) * 3], w1 = w9[(dy + 1) * 3 + 1], w2 = w9[(dy + 1) * 3 + 2];
    d[0] += w0 * v0 + w1 * v1 + w2 * v2;
    d[1] += w0 * v1 + w1 * v2 + w2 * v3;
    d[2] += w0 * v2 + w1 * v3 + w2 * v4;
    d[3] += w0 * v3 + w1 * v4 + w2 * v5;
  }
}

// ---------------- fused q/k/v depthwise + norm + stats (4 px/thread)
__global__ __launch_bounds__(256) void k_dwqkv(const u16* __restrict__ P,
                                               const float* __restrict__ dww,
                                               u16* __restrict__ Qn, u16* __restrict__ Kn,
                                               float* __restrict__ stats) {
  int t = threadIdx.x;
  int lane = t & 63, wv = t >> 6;
  int h = blockIdx.y, b = blockIdx.z;
  int y = blockIdx.x * 4 + wv;
  int x0 = lane * 4;
  long n = (long)y * 256 + x0;
  const u16* Pb = P + (long)b * 192 * NP;

  // q
  float q[8][4], qs[4] = {0.f, 0.f, 0.f, 0.f};
#pragma unroll
  for (int c = 0; c < 8; c++) {
    dw4(Pb + (long)(h * 8 + c) * NP, y, x0, lane, dww + (h * 8 + c) * 9, q[c]);
#pragma unroll
    for (int j = 0; j < 4; j++) qs[j] += q[c][j] * q[c][j];
  }
#pragma unroll
  for (int j = 0; j < 4; j++) qs[j] = 1.f / (sqrtf(qs[j]) + 1e-6f);
#pragma unroll
  for (int c = 0; c < 8; c++) {
    ushort4 st;
    st.x = f2bf(q[c][0] * qs[0]); st.y = f2bf(q[c][1] * qs[1]);
    st.z = f2bf(q[c][2] * qs[2]); st.w = f2bf(q[c][3] * qs[3]);
    *(ushort4*)(Qn + ((long)b * 64 + h * 8 + c) * NP + n) = st;
  }
  // k (reuse q regs)
  float kk[8][4], ks2[4] = {0.f, 0.f, 0.f, 0.f};
#pragma unroll
  for (int c = 0; c < 8; c++) {
    dw4(Pb + (long)(64 + h * 8 + c) * NP, y, x0, lane, dww + (64 + h * 8 + c) * 9, kk[c]);
#pragma unroll
    for (int j = 0; j < 4; j++) ks2[j] += kk[c][j] * kk[c][j];
  }
#pragma unroll
  for (int j = 0; j < 4; j++) ks2[j] = 1.f / (sqrtf(ks2[j]) + 1e-6f);
#pragma unroll
  for (int c = 0; c < 8; c++) {
    ushort4 st;
#pragma unroll
    for (int j = 0; j < 4; j++) kk[c][j] *= ks2[j];
    st.x = f2bf(kk[c][0]); st.y = f2bf(kk[c][1]);
    st.z = f2bf(kk[c][2]); st.w = f2bf(kk[c][3]);
    *(ushort4*)(Kn + ((long)b * 64 + h * 8 + c) * NP + n) = st;
  }
  // v channels one at a time; accumulate kv, ks, vs
  float kv[64], ksum[8], vsum[8];
#pragma unroll
  for (int i = 0; i < 64; i++) kv[i] = 0.f;
#pragma unroll
  for (int i = 0; i < 8; i++) {
    ksum[i] = kk[i][0] + kk[i][1] + kk[i][2] + kk[i][3];
    vsum[i] = 0.f;
  }
#pragma unroll
  for (int jc = 0; jc < 8; jc++) {
    float v4v[4];
    dw4(Pb + (long)(128 + h * 8 + jc) * NP, y, x0, lane, dww + (128 + h * 8 + jc) * 9, v4v);
    vsum[jc] = v4v[0] + v4v[1] + v4v[2] + v4v[3];
#pragma unroll
    for (int i = 0; i < 8; i++)
      kv[i * 8 + jc] += kk[i][0] * v4v[0] + kk[i][1] * v4v[1] +
                        kk[i][2] * v4v[2] + kk[i][3] * v4v[3];
  }
  __shared__ float sred[80];
  if (t < 80) sred[t] = 0.f;
  __syncthreads();
#pragma unroll
  for (int i = 0; i < 64; i++) {
    float a = kv[i];
    for (int off = 32; off; off >>= 1) a += __shfl_down(a, off);
    if (lane == 0) atomicAdd(&sred[i], a);
  }
#pragma unroll
  for (int i = 0; i < 8; i++) {
    float a = ksum[i];
    for (int off = 32; off; off >>= 1) a += __shfl_down(a, off);
    if (lane == 0) atomicAdd(&sred[64 + i], a);
    float c2 = vsum[i];
    for (int off = 32; off; off >>= 1) c2 += __shfl_down(c2, off);
    if (lane == 0) atomicAdd(&sred[72 + i], c2);
  }
  __syncthreads();
  if (t < 80) atomicAdd(&stats[((long)b * 8 + h) * 80 + t], sred[t]);
}

// ---------------- dw1-pairs -> grouped dw2 3x3 -> gelu (4 px/thread)
__global__ __launch_bounds__(256) void k_dwg(const u16* __restrict__ P,
                                             const float* __restrict__ dw2_w,
                                             u16* __restrict__ G) {
  int t = threadIdx.x;
  int lane = t & 63, wv = t >> 6;
  int c = blockIdx.y, b = blockIdx.z;
  int y = blockIdx.x * 4 + wv;
  int x0 = lane * 4;
  long n = (long)y * 256 + x0;
  const u16* Pb = P + (long)b * 128 * NP;
  float d1[4], d2[4];
  dw4(Pb + (long)(2 * c) * NP, y, x0, lane, dw2_w + c * 18, d1);
  dw4(Pb + (long)(2 * c + 1) * NP, y, x0, lane, dw2_w + c * 18 + 9, d2);
  ushort4 st;
  st.x = f2bf(gelu_f(d1[0] + d2[0])); st.y = f2bf(gelu_f(d1[1] + d2[1]));
  st.z = f2bf(gelu_f(d1[2] + d2[2])); st.w = f2bf(gelu_f(d1[3] + d2[3]));
  *(ushort4*)(G + ((long)b * 64 + c) * NP + n) = st;
}

// ---------------- FFN dw pair + gelu gate (pair-interleaved P, 4 px/thread)
__global__ __launch_bounds__(256) void k_dwgate(const u16* __restrict__ P,
                                                const float* __restrict__ dww,
                                                u16* __restrict__ Hb) {
  int t = threadIdx.x;
  int lane = t & 63, wv = t >> 6;
  int c = blockIdx.y, b = blockIdx.z;
  int y = blockIdx.x * 4 + wv;
  int x0 = lane * 4;
  long n = (long)y * 256 + x0;
  const u16* Pb = P + (long)b * 384 * NP;
  float d1[4], d2[4];
  dw4(Pb + (long)(2 * c) * NP, y, x0, lane, dww + c * 9, d1);
  dw4(Pb + (long)(2 * c + 1) * NP, y, x0, lane, dww + (170 + c) * 9, d2);
  ushort4 st;
  st.x = f2bf(gelu_f(d1[0]) * d2[0]); st.y = f2bf(gelu_f(d1[1]) * d2[1]);
  st.z = f2bf(gelu_f(d1[2]) * d2[2]); st.w = f2bf(gelu_f(d1[3]) * d2[3]);
  *(ushort4*)(Hb + ((long)b * 170 + c) * NP + n) = st;
}

// ---------------- refine conv (3/5/7) + sigmoid (R3 version: u16 tile, 4 px/thread)
template <int WIN>
__device__ void refine_body(u16* tile, const u16* __restrict__ Qh, const u16* __restrict__ Kh,
                            const float* __restrict__ wp, float bias,
                            float* __restrict__ ro, int x0, int y0) {
  const int R = WIN / 2, T = 32 + 2 * R, TT = T * T;
  int t = threadIdx.x;
  for (int e = t; e < 16 * TT; e += 256) {
    int ch = e / TT, r = e - ch * TT;
    int yy = r / T, xx = r - yy * T;
    int gy = y0 - R + yy, gx = x0 - R + xx;
    u16 val = 0;
    if ((unsigned)gy < 256u && (unsigned)gx < 256u)
      val = (ch < 8) ? Qh[(long)ch * NP + gy * 256 + gx]
                     : Kh[(long)(ch - 8) * NP + gy * 256 + gx];
    tile[ch * TT + r] = val;
  }
  __syncthreads();
  int oy = t >> 3, ox0 = (t & 7) * 4;
  float a0 = bias, a1 = bias, a2 = bias, a3 = bias;
  for (int ch = 0; ch < 16; ch++) {
    const u16* tp = tile + ch * TT;
    const float* wc = wp + ch * WIN * WIN;
#pragma unroll
    for (int dy = 0; dy < WIN; dy++) {
      const u16* row = tp + (oy + dy) * T + ox0;
      float f[WIN + 3];
#pragma unroll
      for (int k2 = 0; k2 < WIN + 3; k2++) f[k2] = bf2f(row[k2]);
#pragma unroll
      for (int dx = 0; dx < WIN; dx++) {
        float w = wc[dy * WIN + dx];
        a0 += w * f[dx]; a1 += w * f[dx + 1]; a2 += w * f[dx + 2]; a3 += w * f[dx + 3];
      }
    }
  }
  float4 o;
  o.x = 1.f / (1.f + expf(-a0)); o.y = 1.f / (1.f + expf(-a1));
  o.z = 1.f / (1.f + expf(-a2)); o.w = 1.f / (1.f + expf(-a3));
  *(float4*)(ro + (long)(y0 + oy) * 256 + x0 + ox0) = o;
}

__global__ __launch_bounds__(256) void k_refine(
    const u16* __restrict__ Qn, const u16* __restrict__ Kn,
    const float* __restrict__ r3w, const float* __restrict__ r3b,
    const float* __restrict__ r5w, const float* __restrict__ r5b,
    const float* __restrict__ r7w, const float* __restrict__ r7b,
    float* __restrict__ refW) {
  __shared__ u16 tile[16 * 38 * 38];
  int bh = blockIdx.z, b = bh >> 3, h = bh & 7;
  const u16* Qh = Qn + ((long)b * 64 + h * 8) * NP;
  const u16* Kh = Kn + ((long)b * 64 + h * 8) * NP;
  float* ro = refW + (long)bh * NP;
  int x0 = blockIdx.x * 32, y0 = blockIdx.y * 32;
  if (h < 2)      refine_body<3>(tile, Qh, Kh, r3w + h * 16 * 9, r3b[h], ro, x0, y0);
  else if (h < 5) refine_body<5>(tile, Qh, Kh, r5w + (h - 2) * 16 * 25, r5b[h - 2], ro, x0, y0);
  else            refine_body<7>(tile, Qh, Kh, r7w + (h - 5) * 16 * 49, r7b[h - 5], ro, x0, y0);
}

// ---------------- fused attn epilogue + proj GEMM + residual + LN2 + xb2
__global__ __launch_bounds__(256) void k_attnproj(
    const u16* __restrict__ Qn, const float* __restrict__ stats,
    const float* __restrict__ refw, const float* __restrict__ temp,
    const float* __restrict__ xsca, const u16* __restrict__ G,
    const float* __restrict__ WpT, float* __restrict__ xo, u16* __restrict__ xb2) {
  int b = blockIdx.y;
  int t = threadIdx.x;
  __shared__ float s[640];
  __shared__ float sx[64];
  for (int i = t; i < 640; i += 256) s[i] = stats[(long)b * 640 + i];
  if (t < 64) sx[t] = xsca[b * 64 + t];
  __syncthreads();
  long n = (long)blockIdx.x * 256 + t;
  float acc[64];
#pragma unroll
  for (int j = 0; j < 64; j++) acc[j] = 0.f;
#pragma unroll
  for (int h = 0; h < 8; h++) {
    const float* sh = s + h * 80;
    float q[8];
#pragma unroll
    for (int i = 0; i < 8; i++) q[i] = bf2f(Qn[((long)b * 64 + h * 8 + i) * NP + n]);
    float den = 65536.f + 1e-6f;
#pragma unroll
    for (int i = 0; i < 8; i++) den += q[i] * sh[64 + i];
    float tr = temp[h] * refw[((long)b * 8 + h) * NP + n] / den;
#pragma unroll
    for (int j = 0; j < 8; j++) {
      float num = sh[72 + j];
#pragma unroll
      for (int i = 0; i < 8; i++) num += q[i] * sh[i * 8 + j];
      int ci = h * 8 + j;
      float o = num * tr * sx[ci] * bf2f(G[((long)b * 64 + ci) * NP + n]);
      const float* wr = WpT + ci * 64;
#pragma unroll
      for (int co = 0; co < 64; co++) acc[co] += wr[co] * o;
    }
  }
  float* xp = xo + (long)b * 64 * NP + n;
  float s1 = 0.f, s2 = 0.f;
#pragma unroll
  for (int c = 0; c < 64; c++) {
    float v = xp[(long)c * NP] + acc[c];
    acc[c] = v;
    s1 += v; s2 += v * v;
  }
#pragma unroll
  for (int c = 0; c < 64; c++) xp[(long)c * NP] = acc[c];
  float m = s1 * (1.f / 64.f);
  float var = s2 * (1.f / 64.f) - m * m;
  float sg = rsqrtf(var + 1e-5f);
  u16* bp = xb2 + (long)b * 64 * NP + n;
#pragma unroll
  for (int c = 0; c < 64; c++) bp[(long)c * NP] = f2bf(acc[c] * sg);
}

// ---------------- pout GEMM (170->64) + residual
__global__ __launch_bounds__(256) void k_pout(const u16* __restrict__ Hb,
                                              const float* __restrict__ WoT,
                                              float* __restrict__ xo) {
  int n = blockIdx.x * 256 + threadIdx.x;
  int b = blockIdx.z;
  const u16* ip = Hb + (long)b * 170 * NP + n;
  float acc[64];
#pragma unroll
  for (int j = 0; j < 64; j++) acc[j] = 0.f;
#pragma unroll 2
  for (int ci = 0; ci < 170; ci++) {
    float xv = bf2f(ip[(long)ci * NP]);
    const float* wr = WoT + ci * 64;
#pragma unroll
    for (int j = 0; j < 64; j++) acc[j] += wr[j] * xv;
  }
  float* xp = xo + (long)b * 64 * NP + n;
#pragma unroll
  for (int c = 0; c < 64; c++) xp[(long)c * NP] += acc[c];
}

// ================================================================ launcher
extern "C" void kernel_launch(void* const* d_in, const int* in_sizes, int n_in,
                              void* d_out, int out_size, void* d_ws, size_t ws_size,
                              hipStream_t stream) {
  const float* x        = (const float*)d_in[0];
  const float* ln1_w    = (const float*)d_in[1];
  const float* sca_w    = (const float*)d_in[2];
  const float* sca_b    = (const float*)d_in[3];
  const float* dw1_w    = (const float*)d_in[4];
  const float* dw2_w    = (const float*)d_in[5];
  const float* qkv_w    = (const float*)d_in[6];
  const float* qkv_dw_w = (const float*)d_in[7];
  const float* temp     = (const float*)d_in[8];
  const float* r3w = (const float*)d_in[9],  *r3b = (const float*)d_in[10];
  const float* r5w = (const float*)d_in[11], *r5b = (const float*)d_in[12];
  const float* r7w = (const float*)d_in[13], *r7b = (const float*)d_in[14];
  const float* proj_w   = (const float*)d_in[15];
  const float* ln2_w    = (const float*)d_in[16];
  const float* pin_w    = (const float*)d_in[17];
  const float* ffn_dw_w = (const float*)d_in[18];
  const float* pout_w   = (const float*)d_in[19];
  float* out = (float*)d_out;
  char* wsb = (char*)d_ws;

  const size_t Mi = 1048576;
  u16* xb1   = (u16*)(wsb);                 // 32 MiB   (later xb2)
  u16* Qn    = (u16*)(wsb + 32 * Mi);       // 32 MiB   (later Hb start)
  u16* Kn    = (u16*)(wsb + 64 * Mi);
  u16* G     = (u16*)(wsb + 96 * Mi);
  u16* Preg  = (u16*)(wsb + 128 * Mi);      // 96 MiB
  float* refW    = (float*)(wsb + 224 * Mi);// 8 MiB
  float* stats   = (float*)(wsb + 232 * Mi);// 2560
  float* meanraw = stats + 2560;            // 256
  float* xscab   = meanraw + 256;           // 256
  float* W1T     = xscab + 256;             // 64*320
  float* W2T     = W1T + 20480;             // 64*384
  float* WpT     = W2T + 24576;             // 64*64
  float* WoT     = WpT + 4096;              // 170*64
  u16* xb2 = xb1;
  u16* Hb  = Qn;                            // 85 MiB, aliases Qn/Kn/G (dead)

  const size_t needed = 232 * Mi + (size_t)(2560 + 256 + 256 + 20480 + 24576 + 4096 + 10880) * 4;
  if (ws_size < needed) {
    fprintf(stderr, "kernel_launch: ws_size %zu < needed %zu\n", ws_size, needed);
    return;
  }

  hipMemsetAsync(stats, 0, (2560 + 256) * 4, stream);
  k_foldW1<<<80, 256, 0, stream>>>(qkv_w, dw1_w, ln1_w, W1T);
  k_foldW2<<<96, 256, 0, stream>>>(pin_w, ln2_w, W2T);
  k_tproj<<<16, 256, 0, stream>>>(proj_w, WpT);
  k_tpout<<<43, 256, 0, stream>>>(pout_w, WoT);

  k_trans_stats<<<dim3(1024, BB), 256, 0, stream>>>(x, out, xb1, meanraw);
  k_xsca<<<1, 256, 0, stream>>>(meanraw, ln1_w, sca_w, sca_b, xscab);

  // qkv 1x1 (192 co, all batches) -> fused dw+norm+stats
  k_gemm64<<<dim3(256, 3, BB), 256, 0, stream>>>(xb1, W1T, 320, Preg, 192L * NP);
  k_dwqkv<<<dim3(64, 8, BB), 256, 0, stream>>>(Preg, qkv_dw_w, Qn, Kn, stats);

  // dw1 1x1 (128 co) -> grouped dw2 + gelu
  k_gemm64<<<dim3(256, 2, BB), 256, 0, stream>>>(xb1, W1T + 192, 320, Preg, 128L * NP);
  k_dwg<<<dim3(64, 64, BB), 256, 0, stream>>>(Preg, dw2_w, G);

  k_refine<<<dim3(8, 8, 32), 256, 0, stream>>>(Qn, Kn, r3w, r3b, r5w, r5b, r7w, r7b, refW);
  k_attnproj<<<dim3(256, BB), 256, 0, stream>>>(Qn, stats, refW, temp, xscab, G, WpT, out, xb2);

  // FFN: 2 batches per pass
  for (int b2 = 0; b2 < 2; b2++) {
    k_gemm64<<<dim3(256, 6, 2), 256, 0, stream>>>(xb2 + (long)b2 * 2 * 64 * NP, W2T, 384,
                                                  Preg, 384L * NP);
    k_dwgate<<<dim3(64, 170, 2), 256, 0, stream>>>(Preg, ffn_dw_w,
                                                   Hb + (long)b2 * 2 * 170 * NP);
  }
  k_pout<<<dim3(256, 1, BB), 256, 0, stream>>>(Hb, WoT, out);
}

// Round 6
// 1048.889 us; speedup vs baseline: 1.9318x; 1.3426x over previous
//
#include <hip/hip_runtime.h>
#include <math.h>
#include <stdio.h>

#define BB 4
#define NP 65536

typedef unsigned short u16;
typedef unsigned int u32;
typedef __attribute__((ext_vector_type(8))) short short8;
typedef __attribute__((ext_vector_type(4))) float f32x4;

__device__ __forceinline__ float bf2f(u16 u) { return __uint_as_float((u32)u << 16); }
__device__ __forceinline__ u16 f2bf(float f) {
  u32 u = __float_as_uint(f);
  u = (u + 0x7FFFu + ((u >> 16) & 1u)) >> 16;
  return (u16)u;
}
__device__ __forceinline__ float gelu_f(float x) {
  return 0.5f * x * (1.f + erff(x * 0.70710678118654752f));
}

// ---------------- transpose (B,N,C)->(B,C,N) fp32 + xb1 ROW layout bf16 + SCA mean partials
__global__ __launch_bounds__(256) void k_trans_stats(const float* __restrict__ x,
                                                     float* __restrict__ xi,
                                                     u16* __restrict__ xb1,
                                                     float* __restrict__ meanraw) {
  __shared__ float tile[64 * 65];
  __shared__ float s1a[64], s2a[64], sig[64], cm[64];
  int b = blockIdx.y;
  long n0 = (long)blockIdx.x * 64;
  int t = threadIdx.x;
  for (int i = t; i < 4096; i += 256) {
    int nl = i >> 6, c = i & 63;
    tile[nl * 65 + c] = x[((long)b * NP + n0 + nl) * 64 + c];
  }
  if (t < 64) { s1a[t] = 0.f; s2a[t] = 0.f; cm[t] = 0.f; }
  __syncthreads();
  {
    int nl = t & 63, part = t >> 6;
    float p1 = 0.f, p2 = 0.f;
    for (int cc = 0; cc < 16; cc++) {
      float v = tile[nl * 65 + part * 16 + cc];
      p1 += v; p2 += v * v;
    }
    atomicAdd(&s1a[nl], p1); atomicAdd(&s2a[nl], p2);
  }
  __syncthreads();
  if (t < 64) {
    float m = s1a[t] * (1.f / 64.f);
    float var = s2a[t] * (1.f / 64.f) - m * m;
    sig[t] = rsqrtf(var + 1e-5f);
  }
  __syncthreads();
  int nl = t & 63;
  int part = t >> 6;
  float sgv = sig[nl];
  // planar fp32 xi + channel-mean partials
  for (int j = 0; j < 16; j++) {
    int i = t + 256 * j;
    int c = i >> 6;                 // wave-uniform
    float v = tile[nl * 65 + c];
    xi[((long)b * 64 + c) * NP + n0 + nl] = v;
    float a = v * sgv;
    for (int off = 32; off; off >>= 1) a += __shfl_down(a, off);
    if ((t & 63) == 0) atomicAdd(&cm[c], a);
  }
  // xb1 row layout: [px][64ci] bf16, 16 ci per thread packed into 2 dwordx4
  {
    u16* rp = xb1 + ((long)b * NP + n0 + nl) * 64 + part * 16;
    uint4 pk[2];
    u32 tmp[8];
#pragma unroll
    for (int g = 0; g < 2; g++) {
#pragma unroll
      for (int e = 0; e < 4; e++) {
        float v0 = tile[nl * 65 + part * 16 + g * 8 + 2 * e] * sgv;
        float v1 = tile[nl * 65 + part * 16 + g * 8 + 2 * e + 1] * sgv;
        tmp[e] = (u32)f2bf(v0) | ((u32)f2bf(v1) << 16);
      }
      pk[g].x = tmp[0]; pk[g].y = tmp[1]; pk[g].z = tmp[2]; pk[g].w = tmp[3];
      *(uint4*)(rp + g * 8) = pk[g];
    }
  }
  __syncthreads();
  if (t < 64) atomicAdd(&meanraw[b * 64 + t], cm[t]);
}

// ---------------- xsca
__global__ void k_xsca(const float* __restrict__ meanraw, const float* __restrict__ lnw,
                       const float* __restrict__ sca_w, const float* __restrict__ sca_b,
                       float* __restrict__ xsca) {
  int t = threadIdx.x;
  int b = t >> 6, co = t & 63;
  float a = sca_b[co];
  for (int ci = 0; ci < 64; ci++)
    a += sca_w[co * 64 + ci] * meanraw[b * 64 + ci] * lnw[ci] * (1.f / 65536.f);
  xsca[t] = a;
}

// ---------------- weight prep (bf16 [co][64ci], LN folded)
__global__ void k_foldW1b(const float* __restrict__ qkv_w, const float* __restrict__ dw1_w,
                          const float* __restrict__ lnw, u16* __restrict__ W1b) {
  int i = blockIdx.x * 256 + threadIdx.x;
  if (i < 320 * 64) {
    int co = i >> 6, ci = i & 63;
    float w = (co < 192) ? qkv_w[co * 64 + ci] : dw1_w[(co - 192) * 64 + ci];
    W1b[i] = f2bf(w * lnw[ci]);
  }
}
__global__ void k_foldW2b(const float* __restrict__ pin_w, const float* __restrict__ lnw,
                          u16* __restrict__ W2b) {
  int i = blockIdx.x * 256 + threadIdx.x;
  if (i < 384 * 64) {
    int co = i >> 6, ci = i & 63;
    float v = 0.f;
    if (co < 340) {
      int pair = co >> 1, which = co & 1;
      v = pin_w[(pair + which * 170) * 64 + ci] * lnw[ci];
    }
    W2b[i] = f2bf(v);
  }
}
__global__ void k_foldWpb(const float* __restrict__ w, u16* __restrict__ Wpb) {
  int i = blockIdx.x * 256 + threadIdx.x;
  if (i < 4096) Wpb[i] = f2bf(w[i]);   // proj_w already [co][ci]
}
__global__ void k_tpout(const float* __restrict__ w, float* __restrict__ WoT) {
  int i = blockIdx.x * 256 + threadIdx.x;
  if (i < 170 * 64) { int ci = i >> 6, co = i & 63; WoT[ci * 64 + co] = w[co * 170 + ci]; }
}

// ---------------- MFMA GEMM: out[co][px] = sum_ci W[co][ci] * in[px][ci]
// in: row-layout bf16 [px][64]; W: bf16 [co][64]; K=64.
// EPI 0: store bf16 planar.  EPI 1: proj -> residual fp32 + LN2 + xb2 rows.
template <int EPI>
__global__ __launch_bounds__(256) void k_mgemm(const u16* __restrict__ in, long in_bs,
                                               const u16* __restrict__ W,
                                               u16* __restrict__ outp, long out_bs,
                                               float* __restrict__ xo,
                                               u16* __restrict__ xb2r) {
  int t = threadIdx.x;
  int lane = t & 63, wv = t >> 6;
  int l15 = lane & 15, quad = lane >> 4;
  int pxw = blockIdx.x * 256 + wv * 64;
  int co0 = blockIdx.y * 64;
  int b = blockIdx.z;
  const u16* inb = in + (long)b * in_bs;

  short8 aw[4][2];
#pragma unroll
  for (int t4 = 0; t4 < 4; t4++)
#pragma unroll
    for (int kf = 0; kf < 2; kf++)
      aw[t4][kf] = *(const short8*)(W + (long)(co0 + t4 * 16 + l15) * 64 + kf * 32 + quad * 8);

  f32x4 acc[4][4];
#pragma unroll
  for (int t4 = 0; t4 < 4; t4++)
#pragma unroll
    for (int p = 0; p < 4; p++) acc[t4][p] = (f32x4){0.f, 0.f, 0.f, 0.f};

#pragma unroll
  for (int p = 0; p < 4; p++) {
    long px = pxw + p * 16 + l15;
    short8 bf0 = *(const short8*)(inb + px * 64 + quad * 8);
    short8 bf1 = *(const short8*)(inb + px * 64 + 32 + quad * 8);
#pragma unroll
    for (int t4 = 0; t4 < 4; t4++) {
      acc[t4][p] = __builtin_amdgcn_mfma_f32_16x16x32_bf16(aw[t4][0], bf0, acc[t4][p], 0, 0, 0);
      acc[t4][p] = __builtin_amdgcn_mfma_f32_16x16x32_bf16(aw[t4][1], bf1, acc[t4][p], 0, 0, 0);
    }
  }

  if (EPI == 0) {
    u16* ob = outp + (long)b * out_bs;
#pragma unroll
    for (int t4 = 0; t4 < 4; t4++)
#pragma unroll
      for (int p = 0; p < 4; p++) {
#pragma unroll
        for (int reg = 0; reg < 4; reg++) {
          int co = co0 + t4 * 16 + quad * 4 + reg;
          ob[(long)co * NP + pxw + p * 16 + l15] = f2bf(acc[t4][p][reg]);
        }
      }
  } else {
    // proj: CO=64, co0=0. lane holds 16 co (t4*16+quad*4+reg) for px column.
#pragma unroll
    for (int p = 0; p < 4; p++) {
      long px = pxw + p * 16 + l15;
      float xv[16];
      float s1 = 0.f, s2 = 0.f;
#pragma unroll
      for (int t4 = 0; t4 < 4; t4++)
#pragma unroll
        for (int reg = 0; reg < 4; reg++) {
          int co = t4 * 16 + quad * 4 + reg;
          float v = xo[((long)b * 64 + co) * NP + px] + acc[t4][p][reg];
          xv[t4 * 4 + reg] = v;
          s1 += v; s2 += v * v;
        }
      s1 += __shfl_xor(s1, 16); s2 += __shfl_xor(s2, 16);
      s1 += __shfl_xor(s1, 32); s2 += __shfl_xor(s2, 32);
      float m = s1 * (1.f / 64.f);
      float var = s2 * (1.f / 64.f) - m * m;
      float sg = rsqrtf(var + 1e-5f);
#pragma unroll
      for (int t4 = 0; t4 < 4; t4++)
#pragma unroll
        for (int reg = 0; reg < 4; reg++) {
          int co = t4 * 16 + quad * 4 + reg;
          xo[((long)b * 64 + co) * NP + px] = xv[t4 * 4 + reg];
        }
      u16* rp = xb2r + ((long)b * NP + px) * 64;
#pragma unroll
      for (int t4 = 0; t4 < 4; t4++) {
        u32 u0 = (u32)f2bf(xv[t4 * 4 + 0] * sg) | ((u32)f2bf(xv[t4 * 4 + 1] * sg) << 16);
        u32 u1 = (u32)f2bf(xv[t4 * 4 + 2] * sg) | ((u32)f2bf(xv[t4 * 4 + 3] * sg) << 16);
        uint2 pk; pk.x = u0; pk.y = u1;
        *(uint2*)(rp + t4 * 16 + quad * 4) = pk;
      }
    }
  }
}

// ---------------- vectorized dw3x3: 4 px/thread, ushort4 loads, shfl halo
__device__ __forceinline__ void dw4(const u16* __restrict__ img, int y, int x0, int lane,
                                    const float* __restrict__ w9, float d[4]) {
  d[0] = 0.f; d[1] = 0.f; d[2] = 0.f; d[3] = 0.f;
#pragma unroll
  for (int dy = -1; dy <= 1; dy++) {
    int r = y + dy;
    float v1, v2, v3, v4;
    if ((unsigned)r < 256u) {
      ushort4 u = *(const ushort4*)(img + r * 256 + x0);
      v1 = bf2f(u.x); v2 = bf2f(u.y); v3 = bf2f(u.z); v4 = bf2f(u.w);
    } else { v1 = 0.f; v2 = 0.f; v3 = 0.f; v4 = 0.f; }
    float v0 = __shfl_up(v4, 1);  if (lane == 0)  v0 = 0.f;
    float v5 = __shfl_down(v1, 1); if (lane == 63) v5 = 0.f;
    float w0 = w9[(dy + 1) * 3], w1 = w9[(dy + 1) * 3 + 1], w2 = w9[(dy + 1) * 3 + 2];
    d[0] += w0 * v0 + w1 * v1 + w2 * v2;
    d[1] += w0 * v1 + w1 * v2 + w2 * v3;
    d[2] += w0 * v2 + w1 * v3 + w2 * v4;
    d[3] += w0 * v3 + w1 * v4 + w2 * v5;
  }
}

// ---------------- fused q/k/v depthwise + norm + stats
__global__ __launch_bounds__(256) void k_dwqkv(const u16* __restrict__ P,
                                               const float* __restrict__ dww,
                                               u16* __restrict__ Qn, u16* __restrict__ Kn,
                                               float* __restrict__ stats) {
  int t = threadIdx.x;
  int lane = t & 63, wv = t >> 6;
  int h = blockIdx.y, b = blockIdx.z;
  int y = blockIdx.x * 4 + wv;
  int x0 = lane * 4;
  long n = (long)y * 256 + x0;
  const u16* Pb = P + (long)b * 192 * NP;

  float q[8][4], qs[4] = {0.f, 0.f, 0.f, 0.f};
#pragma unroll
  for (int c = 0; c < 8; c++) {
    dw4(Pb + (long)(h * 8 + c) * NP, y, x0, lane, dww + (h * 8 + c) * 9, q[c]);
#pragma unroll
    for (int j = 0; j < 4; j++) qs[j] += q[c][j] * q[c][j];
  }
#pragma unroll
  for (int j = 0; j < 4; j++) qs[j] = 1.f / (sqrtf(qs[j]) + 1e-6f);
#pragma unroll
  for (int c = 0; c < 8; c++) {
    ushort4 st;
    st.x = f2bf(q[c][0] * qs[0]); st.y = f2bf(q[c][1] * qs[1]);
    st.z = f2bf(q[c][2] * qs[2]); st.w = f2bf(q[c][3] * qs[3]);
    *(ushort4*)(Qn + ((long)b * 64 + h * 8 + c) * NP + n) = st;
  }
  float kk[8][4], ks2[4] = {0.f, 0.f, 0.f, 0.f};
#pragma unroll
  for (int c = 0; c < 8; c++) {
    dw4(Pb + (long)(64 + h * 8 + c) * NP, y, x0, lane, dww + (64 + h * 8 + c) * 9, kk[c]);
#pragma unroll
    for (int j = 0; j < 4; j++) ks2[j] += kk[c][j] * kk[c][j];
  }
#pragma unroll
  for (int j = 0; j < 4; j++) ks2[j] = 1.f / (sqrtf(ks2[j]) + 1e-6f);
#pragma unroll
  for (int c = 0; c < 8; c++) {
    ushort4 st;
#pragma unroll
    for (int j = 0; j < 4; j++) kk[c][j] *= ks2[j];
    st.x = f2bf(kk[c][0]); st.y = f2bf(kk[c][1]);
    st.z = f2bf(kk[c][2]); st.w = f2bf(kk[c][3]);
    *(ushort4*)(Kn + ((long)b * 64 + h * 8 + c) * NP + n) = st;
  }
  float kv[64], ksum[8], vsum[8];
#pragma unroll
  for (int i = 0; i < 64; i++) kv[i] = 0.f;
#pragma unroll
  for (int i = 0; i < 8; i++) {
    ksum[i] = kk[i][0] + kk[i][1] + kk[i][2] + kk[i][3];
    vsum[i] = 0.f;
  }
#pragma unroll
  for (int jc = 0; jc < 8; jc++) {
    float v4v[4];
    dw4(Pb + (long)(128 + h * 8 + jc) * NP, y, x0, lane, dww + (128 + h * 8 + jc) * 9, v4v);
    vsum[jc] = v4v[0] + v4v[1] + v4v[2] + v4v[3];
#pragma unroll
    for (int i = 0; i < 8; i++)
      kv[i * 8 + jc] += kk[i][0] * v4v[0] + kk[i][1] * v4v[1] +
                        kk[i][2] * v4v[2] + kk[i][3] * v4v[3];
  }
  __shared__ float sred[80];
  if (t < 80) sred[t] = 0.f;
  __syncthreads();
#pragma unroll
  for (int i = 0; i < 64; i++) {
    float a = kv[i];
    for (int off = 32; off; off >>= 1) a += __shfl_down(a, off);
    if (lane == 0) atomicAdd(&sred[i], a);
  }
#pragma unroll
  for (int i = 0; i < 8; i++) {
    float a = ksum[i];
    for (int off = 32; off; off >>= 1) a += __shfl_down(a, off);
    if (lane == 0) atomicAdd(&sred[64 + i], a);
    float c2 = vsum[i];
    for (int off = 32; off; off >>= 1) c2 += __shfl_down(c2, off);
    if (lane == 0) atomicAdd(&sred[72 + i], c2);
  }
  __syncthreads();
  if (t < 80) atomicAdd(&stats[((long)b * 8 + h) * 80 + t], sred[t]);
}

// ---------------- dw1-pairs -> grouped dw2 3x3 -> gelu
__global__ __launch_bounds__(256) void k_dwg(const u16* __restrict__ P,
                                             const float* __restrict__ dw2_w,
                                             u16* __restrict__ G) {
  int t = threadIdx.x;
  int lane = t & 63, wv = t >> 6;
  int c = blockIdx.y, b = blockIdx.z;
  int y = blockIdx.x * 4 + wv;
  int x0 = lane * 4;
  long n = (long)y * 256 + x0;
  const u16* Pb = P + (long)b * 128 * NP;
  float d1[4], d2[4];
  dw4(Pb + (long)(2 * c) * NP, y, x0, lane, dw2_w + c * 18, d1);
  dw4(Pb + (long)(2 * c + 1) * NP, y, x0, lane, dw2_w + c * 18 + 9, d2);
  ushort4 st;
  st.x = f2bf(gelu_f(d1[0] + d2[0])); st.y = f2bf(gelu_f(d1[1] + d2[1]));
  st.z = f2bf(gelu_f(d1[2] + d2[2])); st.w = f2bf(gelu_f(d1[3] + d2[3]));
  *(ushort4*)(G + ((long)b * 64 + c) * NP + n) = st;
}

// ---------------- FFN dw pair + gelu gate (pair-interleaved P)
__global__ __launch_bounds__(256) void k_dwgate(const u16* __restrict__ P,
                                                const float* __restrict__ dww,
                                                u16* __restrict__ Hb) {
  int t = threadIdx.x;
  int lane = t & 63, wv = t >> 6;
  int c = blockIdx.y, b = blockIdx.z;
  int y = blockIdx.x * 4 + wv;
  int x0 = lane * 4;
  long n = (long)y * 256 + x0;
  const u16* Pb = P + (long)b * 384 * NP;
  float d1[4], d2[4];
  dw4(Pb + (long)(2 * c) * NP, y, x0, lane, dww + c * 9, d1);
  dw4(Pb + (long)(2 * c + 1) * NP, y, x0, lane, dww + (170 + c) * 9, d2);
  ushort4 st;
  st.x = f2bf(gelu_f(d1[0]) * d2[0]); st.y = f2bf(gelu_f(d1[1]) * d2[1]);
  st.z = f2bf(gelu_f(d1[2]) * d2[2]); st.w = f2bf(gelu_f(d1[3]) * d2[3]);
  *(ushort4*)(Hb + ((long)b * 170 + c) * NP + n) = st;
}

// ---------------- refine conv (3/5/7) + sigmoid (u16 tile, 4 px/thread)
template <int WIN>
__device__ void refine_body(u16* tile, const u16* __restrict__ Qh, const u16* __restrict__ Kh,
                            const float* __restrict__ wp, float bias,
                            float* __restrict__ ro, int x0, int y0) {
  const int R = WIN / 2, T = 32 + 2 * R, TT = T * T;
  int t = threadIdx.x;
  for (int e = t; e < 16 * TT; e += 256) {
    int ch = e / TT, r = e - ch * TT;
    int yy = r / T, xx = r - yy * T;
    int gy = y0 - R + yy, gx = x0 - R + xx;
    u16 val = 0;
    if ((unsigned)gy < 256u && (unsigned)gx < 256u)
      val = (ch < 8) ? Qh[(long)ch * NP + gy * 256 + gx]
                     : Kh[(long)(ch - 8) * NP + gy * 256 + gx];
    tile[ch * TT + r] = val;
  }
  __syncthreads();
  int oy = t >> 3, ox0 = (t & 7) * 4;
  float a0 = bias, a1 = bias, a2 = bias, a3 = bias;
  for (int ch = 0; ch < 16; ch++) {
    const u16* tp = tile + ch * TT;
    const float* wc = wp + ch * WIN * WIN;
#pragma unroll
    for (int dy = 0; dy < WIN; dy++) {
      const u16* row = tp + (oy + dy) * T + ox0;
      float f[WIN + 3];
#pragma unroll
      for (int k2 = 0; k2 < WIN + 3; k2++) f[k2] = bf2f(row[k2]);
#pragma unroll
      for (int dx = 0; dx < WIN; dx++) {
        float w = wc[dy * WIN + dx];
        a0 += w * f[dx]; a1 += w * f[dx + 1]; a2 += w * f[dx + 2]; a3 += w * f[dx + 3];
      }
    }
  }
  float4 o;
  o.x = 1.f / (1.f + expf(-a0)); o.y = 1.f / (1.f + expf(-a1));
  o.z = 1.f / (1.f + expf(-a2)); o.w = 1.f / (1.f + expf(-a3));
  *(float4*)(ro + (long)(y0 + oy) * 256 + x0 + ox0) = o;
}

__global__ __launch_bounds__(256) void k_refine(
    const u16* __restrict__ Qn, const u16* __restrict__ Kn,
    const float* __restrict__ r3w, const float* __restrict__ r3b,
    const float* __restrict__ r5w, const float* __restrict__ r5b,
    const float* __restrict__ r7w, const float* __restrict__ r7b,
    float* __restrict__ refW) {
  __shared__ u16 tile[16 * 38 * 38];
  int bh = blockIdx.z, b = bh >> 3, h = bh & 7;
  const u16* Qh = Qn + ((long)b * 64 + h * 8) * NP;
  const u16* Kh = Kn + ((long)b * 64 + h * 8) * NP;
  float* ro = refW + (long)bh * NP;
  int x0 = blockIdx.x * 32, y0 = blockIdx.y * 32;
  if (h < 2)      refine_body<3>(tile, Qh, Kh, r3w + h * 16 * 9, r3b[h], ro, x0, y0);
  else if (h < 5) refine_body<5>(tile, Qh, Kh, r5w + (h - 2) * 16 * 25, r5b[h - 2], ro, x0, y0);
  else            refine_body<7>(tile, Qh, Kh, r7w + (h - 5) * 16 * 49, r7b[h - 5], ro, x0, y0);
}

// ---------------- attention epilogue -> O row layout [px][64]
__global__ __launch_bounds__(256) void k_attn(
    const u16* __restrict__ Qn, const float* __restrict__ stats,
    const float* __restrict__ refw, const float* __restrict__ temp,
    const float* __restrict__ xsca, const u16* __restrict__ G,
    u16* __restrict__ Orows) {
  int b = blockIdx.y;
  int t = threadIdx.x;
  __shared__ float s[640];
  __shared__ float sx[64];
  for (int i = t; i < 640; i += 256) s[i] = stats[(long)b * 640 + i];
  if (t < 64) sx[t] = xsca[b * 64 + t];
  __syncthreads();
  long n = (long)blockIdx.x * 256 + t;
  u16* rp = Orows + ((long)b * NP + n) * 64;
#pragma unroll
  for (int h = 0; h < 8; h++) {
    const float* sh = s + h * 80;
    float q[8];
#pragma unroll
    for (int i = 0; i < 8; i++) q[i] = bf2f(Qn[((long)b * 64 + h * 8 + i) * NP + n]);
    float den = 65536.f + 1e-6f;
#pragma unroll
    for (int i = 0; i < 8; i++) den += q[i] * sh[64 + i];
    float tr = temp[h] * refw[((long)b * 8 + h) * NP + n] / den;
    u32 pk[4];
#pragma unroll
    for (int j2 = 0; j2 < 4; j2++) {
      float o01[2];
#pragma unroll
      for (int e = 0; e < 2; e++) {
        int j = j2 * 2 + e;
        float num = sh[72 + j];
#pragma unroll
        for (int i = 0; i < 8; i++) num += q[i] * sh[i * 8 + j];
        int ci = h * 8 + j;
        o01[e] = num * tr * sx[ci] * bf2f(G[((long)b * 64 + ci) * NP + n]);
      }
      pk[j2] = (u32)f2bf(o01[0]) | ((u32)f2bf(o01[1]) << 16);
    }
    uint4 v; v.x = pk[0]; v.y = pk[1]; v.z = pk[2]; v.w = pk[3];
    *(uint4*)(rp + h * 8) = v;
  }
}

// ---------------- pout GEMM (170->64) + residual (fp32 VALU)
__global__ __launch_bounds__(256) void k_pout(const u16* __restrict__ Hb,
                                              const float* __restrict__ WoT,
                                              float* __restrict__ xo) {
  int n = blockIdx.x * 256 + threadIdx.x;
  int b = blockIdx.z;
  const u16* ip = Hb + (long)b * 170 * NP + n;
  float acc[64];
#pragma unroll
  for (int j = 0; j < 64; j++) acc[j] = 0.f;
#pragma unroll 2
  for (int ci = 0; ci < 170; ci++) {
    float xv = bf2f(ip[(long)ci * NP]);
    const float* wr = WoT + ci * 64;
#pragma unroll
    for (int j = 0; j < 64; j++) acc[j] += wr[j] * xv;
  }
  float* xp = xo + (long)b * 64 * NP + n;
#pragma unroll
  for (int c = 0; c < 64; c++) xp[(long)c * NP] += acc[c];
}

// ================================================================ launcher
extern "C" void kernel_launch(void* const* d_in, const int* in_sizes, int n_in,
                              void* d_out, int out_size, void* d_ws, size_t ws_size,
                              hipStream_t stream) {
  const float* x        = (const float*)d_in[0];
  const float* ln1_w    = (const float*)d_in[1];
  const float* sca_w    = (const float*)d_in[2];
  const float* sca_b    = (const float*)d_in[3];
  const float* dw1_w    = (const float*)d_in[4];
  const float* dw2_w    = (const float*)d_in[5];
  const float* qkv_w    = (const float*)d_in[6];
  const float* qkv_dw_w = (const float*)d_in[7];
  const float* temp     = (const float*)d_in[8];
  const float* r3w = (const float*)d_in[9],  *r3b = (const float*)d_in[10];
  const float* r5w = (const float*)d_in[11], *r5b = (const float*)d_in[12];
  const float* r7w = (const float*)d_in[13], *r7b = (const float*)d_in[14];
  const float* proj_w   = (const float*)d_in[15];
  const float* ln2_w    = (const float*)d_in[16];
  const float* pin_w    = (const float*)d_in[17];
  const float* ffn_dw_w = (const float*)d_in[18];
  const float* pout_w   = (const float*)d_in[19];
  float* out = (float*)d_out;
  char* wsb = (char*)d_ws;

  const size_t Mi = 1048576;
  u16* xb1   = (u16*)(wsb);                  // 32 MiB rows [B][NP][64]  (later xb2)
  u16* Qn    = (u16*)(wsb + 32 * Mi);        // planar
  u16* Kn    = (u16*)(wsb + 64 * Mi);        // planar (later O rows)
  u16* G     = (u16*)(wsb + 96 * Mi);        // planar
  u16* Preg  = (u16*)(wsb + 128 * Mi);       // 96 MiB planar
  float* refW    = (float*)(wsb + 224 * Mi); // 8 MiB
  float* Fm      = (float*)(wsb + 232 * Mi);
  float* stats   = Fm;                       // 2560
  float* meanraw = Fm + 2560;                // 256
  float* xscab   = Fm + 2816;                // 256
  float* WoT     = Fm + 3072;                // 170*64 f32
  u16* W1b = (u16*)(Fm + 13952);             // 320*64 bf16
  u16* W2b = W1b + 20480;                    // 384*64
  u16* Wpb = W2b + 24576;                    // 64*64
  u16* xb2 = xb1;
  u16* Orows = Kn;                           // [B][NP][64] rows
  u16* Hb = Qn;                              // planar [B][170][NP], 85 MiB

  const size_t needed = 232 * Mi + 13952 * 4 + (20480 + 24576 + 4096) * 2;
  if (ws_size < needed) {
    fprintf(stderr, "kernel_launch: ws_size %zu < needed %zu\n", ws_size, needed);
    return;
  }

  hipMemsetAsync(stats, 0, (2560 + 256) * 4, stream);
  k_foldW1b<<<80, 256, 0, stream>>>(qkv_w, dw1_w, ln1_w, W1b);
  k_foldW2b<<<96, 256, 0, stream>>>(pin_w, ln2_w, W2b);
  k_foldWpb<<<16, 256, 0, stream>>>(proj_w, Wpb);
  k_tpout<<<43, 256, 0, stream>>>(pout_w, WoT);

  k_trans_stats<<<dim3(1024, BB), 256, 0, stream>>>(x, out, xb1, meanraw);
  k_xsca<<<1, 256, 0, stream>>>(meanraw, ln1_w, sca_w, sca_b, xscab);

  // qkv 1x1 (MFMA) -> fused dw+norm+stats
  k_mgemm<0><<<dim3(256, 3, BB), 256, 0, stream>>>(xb1, (long)NP * 64, W1b,
                                                   Preg, 192L * NP, nullptr, nullptr);
  k_dwqkv<<<dim3(64, 8, BB), 256, 0, stream>>>(Preg, qkv_dw_w, Qn, Kn, stats);

  // dw1 1x1 (MFMA) -> grouped dw2 + gelu
  k_mgemm<0><<<dim3(256, 2, BB), 256, 0, stream>>>(xb1, (long)NP * 64, W1b + 192 * 64,
                                                   Preg, 128L * NP, nullptr, nullptr);
  k_dwg<<<dim3(64, 64, BB), 256, 0, stream>>>(Preg, dw2_w, G);

  k_refine<<<dim3(8, 8, 32), 256, 0, stream>>>(Qn, Kn, r3w, r3b, r5w, r5b, r7w, r7b, refW);
  k_attn<<<dim3(256, BB), 256, 0, stream>>>(Qn, stats, refW, temp, xscab, G, Orows);

  // proj (MFMA) + residual + LN2 + xb2 rows
  k_mgemm<1><<<dim3(256, 1, BB), 256, 0, stream>>>(Orows, (long)NP * 64, Wpb,
                                                   nullptr, 0, out, xb2);

  // FFN: 2 batches per pass
  for (int pass = 0; pass < 2; pass++) {
    k_mgemm<0><<<dim3(256, 6, 2), 256, 0, stream>>>(xb2 + (long)pass * 2 * NP * 64,
                                                    (long)NP * 64, W2b,
                                                    Preg, 384L * NP, nullptr, nullptr);
    k_dwgate<<<dim3(64, 170, 2), 256, 0, stream>>>(Preg, ffn_dw_w,
                                                   Hb + (long)pass * 2 * 170 * NP);
  }
  k_pout<<<dim3(256, 1, BB), 256, 0, stream>>>(Hb, WoT, out);
}

// Round 7
// 1036.387 us; speedup vs baseline: 1.9551x; 1.0121x over previous
//
#include <hip/hip_runtime.h>
#include <math.h>
#include <stdio.h>

#define BB 4
#define NP 65536

typedef unsigned short u16;
typedef unsigned int u32;
typedef __attribute__((ext_vector_type(8))) short short8;
typedef __attribute__((ext_vector_type(4))) float f32x4;

__device__ __forceinline__ float bf2f(u16 u) { return __uint_as_float((u32)u << 16); }
__device__ __forceinline__ u16 f2bf(float f) {
  u32 u = __float_as_uint(f);
  u = (u + 0x7FFFu + ((u >> 16) & 1u)) >> 16;
  return (u16)u;
}
__device__ __forceinline__ float gelu_f(float x) {
  return 0.5f * x * (1.f + erff(x * 0.70710678118654752f));
}

// ---------------- transpose (B,N,C)->(B,C,N) fp32 + xb1 ROW layout bf16 + SCA mean partials
__global__ __launch_bounds__(256) void k_trans_stats(const float* __restrict__ x,
                                                     float* __restrict__ xi,
                                                     u16* __restrict__ xb1,
                                                     float* __restrict__ meanraw) {
  __shared__ float tile[64 * 65];
  __shared__ float s1a[64], s2a[64], sig[64], cm[64];
  int b = blockIdx.y;
  long n0 = (long)blockIdx.x * 64;
  int t = threadIdx.x;
  for (int i = t; i < 4096; i += 256) {
    int nl = i >> 6, c = i & 63;
    tile[nl * 65 + c] = x[((long)b * NP + n0 + nl) * 64 + c];
  }
  if (t < 64) { s1a[t] = 0.f; s2a[t] = 0.f; cm[t] = 0.f; }
  __syncthreads();
  {
    int nl = t & 63, part = t >> 6;
    float p1 = 0.f, p2 = 0.f;
    for (int cc = 0; cc < 16; cc++) {
      float v = tile[nl * 65 + part * 16 + cc];
      p1 += v; p2 += v * v;
    }
    atomicAdd(&s1a[nl], p1); atomicAdd(&s2a[nl], p2);
  }
  __syncthreads();
  if (t < 64) {
    float m = s1a[t] * (1.f / 64.f);
    float var = s2a[t] * (1.f / 64.f) - m * m;
    sig[t] = rsqrtf(var + 1e-5f);
  }
  __syncthreads();
  int nl = t & 63;
  int part = t >> 6;
  float sgv = sig[nl];
  for (int j = 0; j < 16; j++) {
    int i = t + 256 * j;
    int c = i >> 6;
    float v = tile[nl * 65 + c];
    xi[((long)b * 64 + c) * NP + n0 + nl] = v;
    float a = v * sgv;
    for (int off = 32; off; off >>= 1) a += __shfl_down(a, off);
    if ((t & 63) == 0) atomicAdd(&cm[c], a);
  }
  {
    u16* rp = xb1 + ((long)b * NP + n0 + nl) * 64 + part * 16;
    uint4 pk[2];
    u32 tmp[8];
#pragma unroll
    for (int g = 0; g < 2; g++) {
#pragma unroll
      for (int e = 0; e < 4; e++) {
        float v0 = tile[nl * 65 + part * 16 + g * 8 + 2 * e] * sgv;
        float v1 = tile[nl * 65 + part * 16 + g * 8 + 2 * e + 1] * sgv;
        tmp[e] = (u32)f2bf(v0) | ((u32)f2bf(v1) << 16);
      }
      pk[g].x = tmp[0]; pk[g].y = tmp[1]; pk[g].z = tmp[2]; pk[g].w = tmp[3];
      *(uint4*)(rp + g * 8) = pk[g];
    }
  }
  __syncthreads();
  if (t < 64) atomicAdd(&meanraw[b * 64 + t], cm[t]);
}

// ---------------- xsca
__global__ void k_xsca(const float* __restrict__ meanraw, const float* __restrict__ lnw,
                       const float* __restrict__ sca_w, const float* __restrict__ sca_b,
                       float* __restrict__ xsca) {
  int t = threadIdx.x;
  int b = t >> 6, co = t & 63;
  float a = sca_b[co];
  for (int ci = 0; ci < 64; ci++)
    a += sca_w[co * 64 + ci] * meanraw[b * 64 + ci] * lnw[ci] * (1.f / 65536.f);
  xsca[t] = a;
}

// ---------------- weight prep (bf16 [co][64ci], LN folded)
__global__ void k_foldW1b(const float* __restrict__ qkv_w, const float* __restrict__ dw1_w,
                          const float* __restrict__ lnw, u16* __restrict__ W1b) {
  int i = blockIdx.x * 256 + threadIdx.x;
  if (i < 320 * 64) {
    int co = i >> 6, ci = i & 63;
    float w = (co < 192) ? qkv_w[co * 64 + ci] : dw1_w[(co - 192) * 64 + ci];
    W1b[i] = f2bf(w * lnw[ci]);
  }
}
__global__ void k_foldW2b(const float* __restrict__ pin_w, const float* __restrict__ lnw,
                          u16* __restrict__ W2b) {
  int i = blockIdx.x * 256 + threadIdx.x;
  if (i < 384 * 64) {
    int co = i >> 6, ci = i & 63;
    float v = 0.f;
    if (co < 340) {
      int pair = co >> 1, which = co & 1;
      v = pin_w[(pair + which * 170) * 64 + ci] * lnw[ci];
    }
    W2b[i] = f2bf(v);
  }
}
__global__ void k_foldWpb(const float* __restrict__ w, u16* __restrict__ Wpb) {
  int i = blockIdx.x * 256 + threadIdx.x;
  if (i < 4096) Wpb[i] = f2bf(w[i]);
}
__global__ void k_tpout(const float* __restrict__ w, float* __restrict__ WoT) {
  int i = blockIdx.x * 256 + threadIdx.x;
  if (i < 170 * 64) { int ci = i >> 6, co = i & 63; WoT[ci * 64 + co] = w[co * 170 + ci]; }
}

// ---------------- MFMA GEMM: out[co][px] = sum_ci W[co][ci] * in[px][ci]
template <int EPI>
__global__ __launch_bounds__(256) void k_mgemm(const u16* __restrict__ in, long in_bs,
                                               const u16* __restrict__ W,
                                               u16* __restrict__ outp, long out_bs,
                                               float* __restrict__ xo,
                                               u16* __restrict__ xb2r) {
  int t = threadIdx.x;
  int lane = t & 63, wv = t >> 6;
  int l15 = lane & 15, quad = lane >> 4;
  int pxw = blockIdx.x * 256 + wv * 64;
  int co0 = blockIdx.y * 64;
  int b = blockIdx.z;
  const u16* inb = in + (long)b * in_bs;

  short8 aw[4][2];
#pragma unroll
  for (int t4 = 0; t4 < 4; t4++)
#pragma unroll
    for (int kf = 0; kf < 2; kf++)
      aw[t4][kf] = *(const short8*)(W + (long)(co0 + t4 * 16 + l15) * 64 + kf * 32 + quad * 8);

  f32x4 acc[4][4];
#pragma unroll
  for (int t4 = 0; t4 < 4; t4++)
#pragma unroll
    for (int p = 0; p < 4; p++) acc[t4][p] = (f32x4){0.f, 0.f, 0.f, 0.f};

#pragma unroll
  for (int p = 0; p < 4; p++) {
    long px = pxw + p * 16 + l15;
    short8 bf0 = *(const short8*)(inb + px * 64 + quad * 8);
    short8 bf1 = *(const short8*)(inb + px * 64 + 32 + quad * 8);
#pragma unroll
    for (int t4 = 0; t4 < 4; t4++) {
      acc[t4][p] = __builtin_amdgcn_mfma_f32_16x16x32_bf16(aw[t4][0], bf0, acc[t4][p], 0, 0, 0);
      acc[t4][p] = __builtin_amdgcn_mfma_f32_16x16x32_bf16(aw[t4][1], bf1, acc[t4][p], 0, 0, 0);
    }
  }

  if (EPI == 0) {
    u16* ob = outp + (long)b * out_bs;
#pragma unroll
    for (int t4 = 0; t4 < 4; t4++)
#pragma unroll
      for (int p = 0; p < 4; p++) {
#pragma unroll
        for (int reg = 0; reg < 4; reg++) {
          int co = co0 + t4 * 16 + quad * 4 + reg;
          ob[(long)co * NP + pxw + p * 16 + l15] = f2bf(acc[t4][p][reg]);
        }
      }
  } else {
#pragma unroll
    for (int p = 0; p < 4; p++) {
      long px = pxw + p * 16 + l15;
      float xv[16];
      float s1 = 0.f, s2 = 0.f;
#pragma unroll
      for (int t4 = 0; t4 < 4; t4++)
#pragma unroll
        for (int reg = 0; reg < 4; reg++) {
          int co = t4 * 16 + quad * 4 + reg;
          float v = xo[((long)b * 64 + co) * NP + px] + acc[t4][p][reg];
          xv[t4 * 4 + reg] = v;
          s1 += v; s2 += v * v;
        }
      s1 += __shfl_xor(s1, 16); s2 += __shfl_xor(s2, 16);
      s1 += __shfl_xor(s1, 32); s2 += __shfl_xor(s2, 32);
      float m = s1 * (1.f / 64.f);
      float var = s2 * (1.f / 64.f) - m * m;
      float sg = rsqrtf(var + 1e-5f);
#pragma unroll
      for (int t4 = 0; t4 < 4; t4++)
#pragma unroll
        for (int reg = 0; reg < 4; reg++) {
          int co = t4 * 16 + quad * 4 + reg;
          xo[((long)b * 64 + co) * NP + px] = xv[t4 * 4 + reg];
        }
      u16* rp = xb2r + ((long)b * NP + px) * 64;
#pragma unroll
      for (int t4 = 0; t4 < 4; t4++) {
        u32 u0 = (u32)f2bf(xv[t4 * 4 + 0] * sg) | ((u32)f2bf(xv[t4 * 4 + 1] * sg) << 16);
        u32 u1 = (u32)f2bf(xv[t4 * 4 + 2] * sg) | ((u32)f2bf(xv[t4 * 4 + 3] * sg) << 16);
        uint2 pk; pk.x = u0; pk.y = u1;
        *(uint2*)(rp + t4 * 16 + quad * 4) = pk;
      }
    }
  }
}

// ---------------- vectorized dw3x3: 4 px/thread, ushort4 loads, shfl halo
__device__ __forceinline__ void dw4(const u16* __restrict__ img, int y, int x0, int lane,
                                    const float* __restrict__ w9, float d[4]) {
  d[0] = 0.f; d[1] = 0.f; d[2] = 0.f; d[3] = 0.f;
#pragma unroll
  for (int dy = -1; dy <= 1; dy++) {
    int r = y + dy;
    float v1, v2, v3, v4;
    if ((unsigned)r < 256u) {
      ushort4 u = *(const ushort4*)(img + r * 256 + x0);
      v1 = bf2f(u.x); v2 = bf2f(u.y); v3 = bf2f(u.z); v4 = bf2f(u.w);
    } else { v1 = 0.f; v2 = 0.f; v3 = 0.f; v4 = 0.f; }
    float v0 = __shfl_up(v4, 1);  if (lane == 0)  v0 = 0.f;
    float v5 = __shfl_down(v1, 1); if (lane == 63) v5 = 0.f;
    float w0 = w9[(dy + 1) * 3], w1 = w9[(dy + 1) * 3 + 1], w2 = w9[(dy + 1) * 3 + 2];
    d[0] += w0 * v0 + w1 * v1 + w2 * v2;
    d[1] += w0 * v1 + w1 * v2 + w2 * v3;
    d[2] += w0 * v2 + w1 * v3 + w2 * v4;
    d[3] += w0 * v3 + w1 * v4 + w2 * v5;
  }
}

// ---------------- fused q/k/v depthwise + norm + stats
__global__ __launch_bounds__(256) void k_dwqkv(const u16* __restrict__ P,
                                               const float* __restrict__ dww,
                                               u16* __restrict__ Qn, u16* __restrict__ Kn,
                                               float* __restrict__ stats) {
  int t = threadIdx.x;
  int lane = t & 63, wv = t >> 6;
  int h = blockIdx.y, b = blockIdx.z;
  int y = blockIdx.x * 4 + wv;
  int x0 = lane * 4;
  long n = (long)y * 256 + x0;
  const u16* Pb = P + (long)b * 192 * NP;

  float q[8][4], qs[4] = {0.f, 0.f, 0.f, 0.f};
#pragma unroll
  for (int c = 0; c < 8; c++) {
    dw4(Pb + (long)(h * 8 + c) * NP, y, x0, lane, dww + (h * 8 + c) * 9, q[c]);
#pragma unroll
    for (int j = 0; j < 4; j++) qs[j] += q[c][j] * q[c][j];
  }
#pragma unroll
  for (int j = 0; j < 4; j++) qs[j] = 1.f / (sqrtf(qs[j]) + 1e-6f);
#pragma unroll
  for (int c = 0; c < 8; c++) {
    ushort4 st;
    st.x = f2bf(q[c][0] * qs[0]); st.y = f2bf(q[c][1] * qs[1]);
    st.z = f2bf(q[c][2] * qs[2]); st.w = f2bf(q[c][3] * qs[3]);
    *(ushort4*)(Qn + ((long)b * 64 + h * 8 + c) * NP + n) = st;
  }
  float kk[8][4], ks2[4] = {0.f, 0.f, 0.f, 0.f};
#pragma unroll
  for (int c = 0; c < 8; c++) {
    dw4(Pb + (long)(64 + h * 8 + c) * NP, y, x0, lane, dww + (64 + h * 8 + c) * 9, kk[c]);
#pragma unroll
    for (int j = 0; j < 4; j++) ks2[j] += kk[c][j] * kk[c][j];
  }
#pragma unroll
  for (int j = 0; j < 4; j++) ks2[j] = 1.f / (sqrtf(ks2[j]) + 1e-6f);
#pragma unroll
  for (int c = 0; c < 8; c++) {
    ushort4 st;
#pragma unroll
    for (int j = 0; j < 4; j++) kk[c][j] *= ks2[j];
    st.x = f2bf(kk[c][0]); st.y = f2bf(kk[c][1]);
    st.z = f2bf(kk[c][2]); st.w = f2bf(kk[c][3]);
    *(ushort4*)(Kn + ((long)b * 64 + h * 8 + c) * NP + n) = st;
  }
  float kv[64], ksum[8], vsum[8];
#pragma unroll
  for (int i = 0; i < 64; i++) kv[i] = 0.f;
#pragma unroll
  for (int i = 0; i < 8; i++) {
    ksum[i] = kk[i][0] + kk[i][1] + kk[i][2] + kk[i][3];
    vsum[i] = 0.f;
  }
#pragma unroll
  for (int jc = 0; jc < 8; jc++) {
    float v4v[4];
    dw4(Pb + (long)(128 + h * 8 + jc) * NP, y, x0, lane, dww + (128 + h * 8 + jc) * 9, v4v);
    vsum[jc] = v4v[0] + v4v[1] + v4v[2] + v4v[3];
#pragma unroll
    for (int i = 0; i < 8; i++)
      kv[i * 8 + jc] += kk[i][0] * v4v[0] + kk[i][1] * v4v[1] +
                        kk[i][2] * v4v[2] + kk[i][3] * v4v[3];
  }
  __shared__ float sred[80];
  if (t < 80) sred[t] = 0.f;
  __syncthreads();
#pragma unroll
  for (int i = 0; i < 64; i++) {
    float a = kv[i];
    for (int off = 32; off; off >>= 1) a += __shfl_down(a, off);
    if (lane == 0) atomicAdd(&sred[i], a);
  }
#pragma unroll
  for (int i = 0; i < 8; i++) {
    float a = ksum[i];
    for (int off = 32; off; off >>= 1) a += __shfl_down(a, off);
    if (lane == 0) atomicAdd(&sred[64 + i], a);
    float c2 = vsum[i];
    for (int off = 32; off; off >>= 1) c2 += __shfl_down(c2, off);
    if (lane == 0) atomicAdd(&sred[72 + i], c2);
  }
  __syncthreads();
  if (t < 80) atomicAdd(&stats[((long)b * 8 + h) * 80 + t], sred[t]);
}

// ---------------- dw1-pairs -> grouped dw2 3x3 -> gelu
__global__ __launch_bounds__(256) void k_dwg(const u16* __restrict__ P,
                                             const float* __restrict__ dw2_w,
                                             u16* __restrict__ G) {
  int t = threadIdx.x;
  int lane = t & 63, wv = t >> 6;
  int c = blockIdx.y, b = blockIdx.z;
  int y = blockIdx.x * 4 + wv;
  int x0 = lane * 4;
  long n = (long)y * 256 + x0;
  const u16* Pb = P + (long)b * 128 * NP;
  float d1[4], d2[4];
  dw4(Pb + (long)(2 * c) * NP, y, x0, lane, dw2_w + c * 18, d1);
  dw4(Pb + (long)(2 * c + 1) * NP, y, x0, lane, dw2_w + c * 18 + 9, d2);
  ushort4 st;
  st.x = f2bf(gelu_f(d1[0] + d2[0])); st.y = f2bf(gelu_f(d1[1] + d2[1]));
  st.z = f2bf(gelu_f(d1[2] + d2[2])); st.w = f2bf(gelu_f(d1[3] + d2[3]));
  *(ushort4*)(G + ((long)b * 64 + c) * NP + n) = st;
}

// ---------------- FFN dw pair + gelu gate (pair-interleaved P)
__global__ __launch_bounds__(256) void k_dwgate(const u16* __restrict__ P,
                                                const float* __restrict__ dww,
                                                u16* __restrict__ Hb) {
  int t = threadIdx.x;
  int lane = t & 63, wv = t >> 6;
  int c = blockIdx.y, b = blockIdx.z;
  int y = blockIdx.x * 4 + wv;
  int x0 = lane * 4;
  long n = (long)y * 256 + x0;
  const u16* Pb = P + (long)b * 384 * NP;
  float d1[4], d2[4];
  dw4(Pb + (long)(2 * c) * NP, y, x0, lane, dww + c * 9, d1);
  dw4(Pb + (long)(2 * c + 1) * NP, y, x0, lane, dww + (170 + c) * 9, d2);
  ushort4 st;
  st.x = f2bf(gelu_f(d1[0]) * d2[0]); st.y = f2bf(gelu_f(d1[1]) * d2[1]);
  st.z = f2bf(gelu_f(d1[2]) * d2[2]); st.w = f2bf(gelu_f(d1[3]) * d2[3]);
  *(ushort4*)(Hb + ((long)b * 170 + c) * NP + n) = st;
}

// ---------------- refine conv (3/5/7) + sigmoid: 2 phases x 8ch, u16 tile pitch 40,
// vector staging (ushort4->b64) and 3x ds_read_b64 per (ch,row)
template <int WIN>
__device__ void refine_body(u16* tile, const u16* __restrict__ Qh, const u16* __restrict__ Kh,
                            const float* __restrict__ wp, float bias,
                            float* __restrict__ ro, int x0, int y0) {
  const int R = WIN / 2, TR = 32 + 2 * R;   // rows
  int t = threadIdx.x;
  int oy = t >> 3, ox0 = (t & 7) * 4;
  float a0 = bias, a1 = bias, a2 = bias, a3 = bias;
#pragma unroll
  for (int ph = 0; ph < 2; ph++) {
    const u16* src = ph ? Kh : Qh;
    __syncthreads();
    // stage 8ch x TR rows x 40 cols (x window [x0-4, x0+36), 4-aligned -> whole-vector mask)
    for (int e = t; e < 8 * TR * 10; e += 256) {
      int ch = e / (TR * 10); int r = e - ch * (TR * 10);
      int ry = r / 10, k4 = r - ry * 10;
      int gy = y0 - R + ry, gx = x0 - 4 + k4 * 4;
      ushort4 val = {0, 0, 0, 0};
      if ((unsigned)gy < 256u && (unsigned)gx < 256u)
        val = *(const ushort4*)(src + (long)ch * NP + gy * 256 + gx);
      *(ushort4*)(tile + ch * (TR * 40) + ry * 40 + k4 * 4) = val;
    }
    __syncthreads();
    for (int ch = 0; ch < 8; ch++) {
      const float* wc = wp + (ph * 8 + ch) * WIN * WIN;
      const u16* tb = tile + ch * (TR * 40);
#pragma unroll
      for (int dy = 0; dy < WIN; dy++) {
        const u16* row = tb + (oy + dy) * 40 + ox0;
        ushort4 u0 = *(const ushort4*)(row);
        ushort4 u1 = *(const ushort4*)(row + 4);
        ushort4 u2 = *(const ushort4*)(row + 8);
        float f[12];
        f[0] = bf2f(u0.x); f[1] = bf2f(u0.y); f[2] = bf2f(u0.z); f[3] = bf2f(u0.w);
        f[4] = bf2f(u1.x); f[5] = bf2f(u1.y); f[6] = bf2f(u1.z); f[7] = bf2f(u1.w);
        f[8] = bf2f(u2.x); f[9] = bf2f(u2.y); f[10] = bf2f(u2.z); f[11] = bf2f(u2.w);
#pragma unroll
        for (int dx = 0; dx < WIN; dx++) {
          float w = wc[dy * WIN + dx];
          const int o = 4 - R + dx;
          a0 += w * f[o]; a1 += w * f[o + 1]; a2 += w * f[o + 2]; a3 += w * f[o + 3];
        }
      }
    }
  }
  float4 o;
  o.x = 1.f / (1.f + expf(-a0)); o.y = 1.f / (1.f + expf(-a1));
  o.z = 1.f / (1.f + expf(-a2)); o.w = 1.f / (1.f + expf(-a3));
  *(float4*)(ro + (long)(y0 + oy) * 256 + x0 + ox0) = o;
}

__global__ __launch_bounds__(256) void k_refine(
    const u16* __restrict__ Qn, const u16* __restrict__ Kn,
    const float* __restrict__ r3w, const float* __restrict__ r3b,
    const float* __restrict__ r5w, const float* __restrict__ r5b,
    const float* __restrict__ r7w, const float* __restrict__ r7b,
    float* __restrict__ refW) {
  __shared__ u16 tile[8 * 38 * 40];   // 24320 B
  int bh = blockIdx.z, b = bh >> 3, h = bh & 7;
  const u16* Qh = Qn + ((long)b * 64 + h * 8) * NP;
  const u16* Kh = Kn + ((long)b * 64 + h * 8) * NP;
  float* ro = refW + (long)bh * NP;
  int x0 = blockIdx.x * 32, y0 = blockIdx.y * 32;
  if (h < 2)      refine_body<3>(tile, Qh, Kh, r3w + h * 16 * 9, r3b[h], ro, x0, y0);
  else if (h < 5) refine_body<5>(tile, Qh, Kh, r5w + (h - 2) * 16 * 25, r5b[h - 2], ro, x0, y0);
  else            refine_body<7>(tile, Qh, Kh, r7w + (h - 5) * 16 * 49, r7b[h - 5], ro, x0, y0);
}

// ---------------- attention epilogue -> O row layout [px][64]
__global__ __launch_bounds__(256) void k_attn(
    const u16* __restrict__ Qn, const float* __restrict__ stats,
    const float* __restrict__ refw, const float* __restrict__ temp,
    const float* __restrict__ xsca, const u16* __restrict__ G,
    u16* __restrict__ Orows) {
  int b = blockIdx.y;
  int t = threadIdx.x;
  __shared__ float s[640];
  __shared__ float sx[64];
  for (int i = t; i < 640; i += 256) s[i] = stats[(long)b * 640 + i];
  if (t < 64) sx[t] = xsca[b * 64 + t];
  __syncthreads();
  long n = (long)blockIdx.x * 256 + t;
  u16* rp = Orows + ((long)b * NP + n) * 64;
#pragma unroll
  for (int h = 0; h < 8; h++) {
    const float* sh = s + h * 80;
    float q[8];
#pragma unroll
    for (int i = 0; i < 8; i++) q[i] = bf2f(Qn[((long)b * 64 + h * 8 + i) * NP + n]);
    float den = 65536.f + 1e-6f;
#pragma unroll
    for (int i = 0; i < 8; i++) den += q[i] * sh[64 + i];
    float tr = temp[h] * refw[((long)b * 8 + h) * NP + n] / den;
    u32 pk[4];
#pragma unroll
    for (int j2 = 0; j2 < 4; j2++) {
      float o01[2];
#pragma unroll
      for (int e = 0; e < 2; e++) {
        int j = j2 * 2 + e;
        float num = sh[72 + j];
#pragma unroll
        for (int i = 0; i < 8; i++) num += q[i] * sh[i * 8 + j];
        int ci = h * 8 + j;
        o01[e] = num * tr * sx[ci] * bf2f(G[((long)b * 64 + ci) * NP + n]);
      }
      pk[j2] = (u32)f2bf(o01[0]) | ((u32)f2bf(o01[1]) << 16);
    }
    uint4 v; v.x = pk[0]; v.y = pk[1]; v.z = pk[2]; v.w = pk[3];
    *(uint4*)(rp + h * 8) = v;
  }
}

// ---------------- pout GEMM (170->64) + residual (fp32 VALU)
__global__ __launch_bounds__(256) void k_pout(const u16* __restrict__ Hb,
                                              const float* __restrict__ WoT,
                                              float* __restrict__ xo) {
  int n = blockIdx.x * 256 + threadIdx.x;
  int b = blockIdx.z;
  const u16* ip = Hb + (long)b * 170 * NP + n;
  float acc[64];
#pragma unroll
  for (int j = 0; j < 64; j++) acc[j] = 0.f;
#pragma unroll 2
  for (int ci = 0; ci < 170; ci++) {
    float xv = bf2f(ip[(long)ci * NP]);
    const float* wr = WoT + ci * 64;
#pragma unroll
    for (int j = 0; j < 64; j++) acc[j] += wr[j] * xv;
  }
  float* xp = xo + (long)b * 64 * NP + n;
#pragma unroll
  for (int c = 0; c < 64; c++) xp[(long)c * NP] += acc[c];
}

// ================================================================ launcher
extern "C" void kernel_launch(void* const* d_in, const int* in_sizes, int n_in,
                              void* d_out, int out_size, void* d_ws, size_t ws_size,
                              hipStream_t stream) {
  const float* x        = (const float*)d_in[0];
  const float* ln1_w    = (const float*)d_in[1];
  const float* sca_w    = (const float*)d_in[2];
  const float* sca_b    = (const float*)d_in[3];
  const float* dw1_w    = (const float*)d_in[4];
  const float* dw2_w    = (const float*)d_in[5];
  const float* qkv_w    = (const float*)d_in[6];
  const float* qkv_dw_w = (const float*)d_in[7];
  const float* temp     = (const float*)d_in[8];
  const float* r3w = (const float*)d_in[9],  *r3b = (const float*)d_in[10];
  const float* r5w = (const float*)d_in[11], *r5b = (const float*)d_in[12];
  const float* r7w = (const float*)d_in[13], *r7b = (const float*)d_in[14];
  const float* proj_w   = (const float*)d_in[15];
  const float* ln2_w    = (const float*)d_in[16];
  const float* pin_w    = (const float*)d_in[17];
  const float* ffn_dw_w = (const float*)d_in[18];
  const float* pout_w   = (const float*)d_in[19];
  float* out = (float*)d_out;
  char* wsb = (char*)d_ws;

  const size_t Mi = 1048576;
  u16* xb1   = (u16*)(wsb);                  // rows [B][NP][64]  (later xb2)
  u16* Qn    = (u16*)(wsb + 32 * Mi);        // planar
  u16* Kn    = (u16*)(wsb + 64 * Mi);        // planar (later O rows)
  u16* G     = (u16*)(wsb + 96 * Mi);        // planar
  u16* Preg  = (u16*)(wsb + 128 * Mi);       // 96 MiB planar
  float* refW    = (float*)(wsb + 224 * Mi); // 8 MiB
  float* Fm      = (float*)(wsb + 232 * Mi);
  float* stats   = Fm;
  float* meanraw = Fm + 2560;
  float* xscab   = Fm + 2816;
  float* WoT     = Fm + 3072;
  u16* W1b = (u16*)(Fm + 13952);
  u16* W2b = W1b + 20480;
  u16* Wpb = W2b + 24576;
  u16* xb2 = xb1;
  u16* Orows = Kn;
  u16* Hb = Qn;

  const size_t needed = 232 * Mi + 13952 * 4 + (20480 + 24576 + 4096) * 2;
  if (ws_size < needed) {
    fprintf(stderr, "kernel_launch: ws_size %zu < needed %zu\n", ws_size, needed);
    return;
  }

  hipMemsetAsync(stats, 0, (2560 + 256) * 4, stream);
  k_foldW1b<<<80, 256, 0, stream>>>(qkv_w, dw1_w, ln1_w, W1b);
  k_foldW2b<<<96, 256, 0, stream>>>(pin_w, ln2_w, W2b);
  k_foldWpb<<<16, 256, 0, stream>>>(proj_w, Wpb);
  k_tpout<<<43, 256, 0, stream>>>(pout_w, WoT);

  k_trans_stats<<<dim3(1024, BB), 256, 0, stream>>>(x, out, xb1, meanraw);
  k_xsca<<<1, 256, 0, stream>>>(meanraw, ln1_w, sca_w, sca_b, xscab);

  k_mgemm<0><<<dim3(256, 3, BB), 256, 0, stream>>>(xb1, (long)NP * 64, W1b,
                                                   Preg, 192L * NP, nullptr, nullptr);
  k_dwqkv<<<dim3(64, 8, BB), 256, 0, stream>>>(Preg, qkv_dw_w, Qn, Kn, stats);

  k_mgemm<0><<<dim3(256, 2, BB), 256, 0, stream>>>(xb1, (long)NP * 64, W1b + 192 * 64,
                                                   Preg, 128L * NP, nullptr, nullptr);
  k_dwg<<<dim3(64, 64, BB), 256, 0, stream>>>(Preg, dw2_w, G);

  k_refine<<<dim3(8, 8, 32), 256, 0, stream>>>(Qn, Kn, r3w, r3b, r5w, r5b, r7w, r7b, refW);
  k_attn<<<dim3(256, BB), 256, 0, stream>>>(Qn, stats, refW, temp, xscab, G, Orows);

  k_mgemm<1><<<dim3(256, 1, BB), 256, 0, stream>>>(Orows, (long)NP * 64, Wpb,
                                                   nullptr, 0, out, xb2);

  for (int pass = 0; pass < 2; pass++) {
    k_mgemm<0><<<dim3(256, 6, 2), 256, 0, stream>>>(xb2 + (long)pass * 2 * NP * 64,
                                                    (long)NP * 64, W2b,
                                                    Preg, 384L * NP, nullptr, nullptr);
    k_dwgate<<<dim3(64, 170, 2), 256, 0, stream>>>(Preg, ffn_dw_w,
                                                   Hb + (long)pass * 2 * 170 * NP);
  }
  k_pout<<<dim3(256, 1, BB), 256, 0, stream>>>(Hb, WoT, out);
}